// Round 9
// baseline (255.164 us; speedup 1.0000x reference)
//
#include <hip/hip_runtime.h>
#include <hip/hip_bf16.h>
#include <cmath>

// Problem constants (fixed by the reference)
constexpr int CB  = 8;     // batch
constexpr int CN  = 1024;  // sequence length
constexpr int CD  = 256;   // model dim
constexpr int CH  = 8;     // heads
constexpr int CDH = 32;    // head dim
constexpr int CR  = 4;     // relation types (adj value 4 = none)
constexpr int CFF = 1024;  // ffn dim
constexpr float CEPS = 1e-5f;
constexpr size_t SZH = (size_t)CB * CH * CN * CDH;  // 2M: one head-plane

#define MODE_QK    0   // scatter bf16 q/k head-major planes, +bias (cols 0..511)
#define MODE_FFN1  2   // +bias, tanh-gelu -> bf16
#define MODE_VT    4   // V^T gemm (A=weight rows, B=src rows): coalesced store

typedef float v4f __attribute__((ext_vector_type(4)));
typedef short v8s __attribute__((ext_vector_type(8)));

static __device__ __forceinline__ short f2bf(float f) {
    unsigned u = __builtin_bit_cast(unsigned, f);
    u += 0x7fff + ((u >> 16) & 1);          // round-to-nearest-even
    return (short)(u >> 16);
}

static __device__ __forceinline__ void async_copy16(const void* g, void* l) {
    __builtin_amdgcn_global_load_lds(
        (const __attribute__((address_space(1))) void*)g,
        (__attribute__((address_space(3))) void*)l, 16, 0, 0);
}

// ---------------------------------------------------------------------------
// bf16 MFMA GEMM body (device fn, dynamic LDS): epilogue(A[M,K] @ Bw[N,K])
// BM x BN tile, 4 waves 2x2, BK=32 double-buffered 1-deep prefetch.
// ---------------------------------------------------------------------------
template<int BM, int BN, int MODE>
__device__ __forceinline__ void gemm_body(
    const short* __restrict__ A, const short* __restrict__ Bw,
    const float* __restrict__ biasv, void* __restrict__ dest,
    int M, int K, int Nw, int bx, int by, short* smem)
{
    constexpr int WTM = BM / 2, WTN = BN / 2;
    constexpr int TM = WTM / 16, TN = WTN / 16;
    short* As = smem;                    // [2][BM*32]
    short* Bs = smem + 2 * BM * 32;      // [2][BN*32]

    const int t    = threadIdx.x;
    const int lane = t & 63;
    const int w    = t >> 6;
    const int quad = lane >> 4, l15 = lane & 15;
    const int wm = w >> 1, wn = w & 1;
    const int m0 = bx * BM, n0 = by * BN;

    const int srow = lane >> 2;
    const int scol = (lane & 3) * 8;

    v4f acc[TM][TN];
    #pragma unroll
    for (int i = 0; i < TM; ++i)
        #pragma unroll
        for (int j = 0; j < TN; ++j) acc[i][j] = (v4f){0.f, 0.f, 0.f, 0.f};

    const int NK = K >> 5;

    auto stage = [&](int buf, int kt) {
        #pragma unroll
        for (int u = 0; u < BM / 64; ++u) {
            const int e0 = (w * (BM / 64) + u) * 512;
            const int row = (e0 >> 5) + srow;
            async_copy16(A + (size_t)(m0 + row) * K + kt + scol,
                         &As[buf * BM * 32 + e0]);
        }
        #pragma unroll
        for (int u = 0; u < BN / 64; ++u) {
            const int e0 = (w * (BN / 64) + u) * 512;
            const int row = (e0 >> 5) + srow;
            async_copy16(Bw + (size_t)(n0 + row) * K + kt + scol,
                         &Bs[buf * BN * 32 + e0]);
        }
    };

    stage(0, 0);

    for (int it = 0; it < NK; ++it) {
        __syncthreads();
        if (it + 1 < NK) stage((it + 1) & 1, (it + 1) << 5);

        const int buf = it & 1;
        v8s af[TM], bfr[TN];
        #pragma unroll
        for (int i = 0; i < TM; ++i)
            af[i] = *(const v8s*)&As[buf * BM * 32 +
                                     (wm * WTM + i * 16 + l15) * 32 + quad * 8];
        #pragma unroll
        for (int j = 0; j < TN; ++j)
            bfr[j] = *(const v8s*)&Bs[buf * BN * 32 +
                                      (wn * WTN + j * 16 + l15) * 32 + quad * 8];
        #pragma unroll
        for (int i = 0; i < TM; ++i)
            #pragma unroll
            for (int j = 0; j < TN; ++j)
                acc[i][j] = __builtin_amdgcn_mfma_f32_16x16x32_bf16(
                    af[i], bfr[j], acc[i][j], 0, 0, 0);
    }

    #pragma unroll
    for (int i = 0; i < TM; ++i) {
        #pragma unroll
        for (int j = 0; j < TN; ++j) {
            const int mb = m0 + wm * WTM + i * 16 + quad * 4;   // row of rr=0
            const int n  = n0 + wn * WTN + j * 16 + l15;
            float vals[4];
            if (MODE == MODE_VT) {
                #pragma unroll
                for (int rr = 0; rr < 4; ++rr) vals[rr] = acc[i][j][rr] + biasv[mb + rr];
            } else {
                #pragma unroll
                for (int rr = 0; rr < 4; ++rr) vals[rr] = acc[i][j][rr] + biasv[n];
            }

            if (MODE == MODE_QK) {
                const int b = mb >> 10, ii0 = mb & 1023;
                const int plane = n >> 8, nn = n & 255;
                const int h = nn >> 5, d = nn & 31;
                #pragma unroll
                for (int rr = 0; rr < 4; ++rr)
                    ((short*)dest)[(size_t)plane * SZH +
                        (((size_t)(b * CH + h)) * CN + ii0 + rr) * CDH + d] =
                        f2bf(vals[rr]);
            } else if (MODE == MODE_VT) {
                const int b = n >> 10, ii = n & 1023;
                #pragma unroll
                for (int rr = 0; rr < 4; ++rr) {
                    const int m = mb + rr;
                    const int r2 = m >> 8, hd = m & 255;
                    const int h = hd >> 5, d = hd & 31;
                    ((short*)dest)[2 * SZH +
                        (((size_t)(r2 * 64 + b * CH + h)) * CDH + d) * CN + ii] =
                        f2bf(vals[rr]);
                }
            } else { // MODE_FFN1: tanh-gelu -> bf16 (x*E/(E+1))
                #pragma unroll
                for (int rr = 0; rr < 4; ++rr) {
                    const size_t idx = (size_t)(mb + rr) * Nw + n;
                    const float xx = vals[rr];
                    const float E = exp2f(2.302217f * (xx + 0.044715f * xx * xx * xx));
                    ((short*)dest)[idx] = f2bf(xx * E / (E + 1.f));
                }
            }
        }
    }
}

template<int BM, int BN, int MODE>
__global__ __launch_bounds__(256)
void gemm_mfma(const short* __restrict__ A, const short* __restrict__ Bw,
               const float* __restrict__ biasv, void* __restrict__ dest,
               int M, int K, int Nw)
{
    extern __shared__ short smem[];
    gemm_body<BM, BN, MODE>(A, Bw, biasv, dest, M, K, Nw,
                            blockIdx.x, blockIdx.y, smem);
}

// Fused projection dispatch: blocks 0..511 = QK (8192x512), 512..1535 = V^T.
__global__ __launch_bounds__(256)
void proj_kernel(const short* __restrict__ src_bf, const short* __restrict__ wqkvT,
                 const float* __restrict__ bpack, short* __restrict__ qkv)
{
    extern __shared__ short smem[];
    const int g = blockIdx.x;
    if (g < 512) {
        gemm_body<64, 128, MODE_QK>(src_bf, wqkvT, bpack, qkv,
                                    8192, 256, 512, g >> 2, g & 3, smem);
    } else {
        const int h2 = g - 512;
        gemm_body<64, 128, MODE_VT>(wqkvT + 512 * 256, src_bf, bpack + 512,
                                    qkv, 1024, 256, 8192, h2 & 15, h2 >> 4, smem);
    }
}

// ---------------------------------------------------------------------------
// FUSED GEMM + bias + residual + LayerNorm.  BM=64, BN=256 == Nw (full rows
// in one block), 4 waves as 4 ROW-groups (wave-local LN: each wave owns 16
// complete rows; row-reduce = 4 xor-shuffles within a 16-lane group).
// outf (fp32) always; outb (bf16) optionally.
// ---------------------------------------------------------------------------
template<bool WRITE_BF>
__global__ __launch_bounds__(256)
void gemm_ln(const short* __restrict__ A, const short* __restrict__ Bw,
             const float* __restrict__ biasv, const float* __restrict__ add,
             const float* __restrict__ gw, const float* __restrict__ be,
             float* __restrict__ outf, short* __restrict__ outb, int K)
{
    __shared__ short As[2][64 * 32];
    __shared__ short Bs[2][256 * 32];

    const int t    = threadIdx.x;
    const int lane = t & 63;
    const int w    = t >> 6;          // wave = row group (16 rows)
    const int quad = lane >> 4, l15 = lane & 15;
    const int m0   = blockIdx.x * 64;

    const int srow = lane >> 2;
    const int scol = (lane & 3) * 8;

    v4f acc[16];
    #pragma unroll
    for (int j = 0; j < 16; ++j) acc[j] = (v4f){0.f, 0.f, 0.f, 0.f};

    const int NK = K >> 5;

    auto stage = [&](int buf, int kt) {
        // A: 64 rows, 1 DMA/thread (wave-uniform LDS base + lane*16B)
        async_copy16(A + (size_t)(m0 + 16 * w + srow) * K + kt + scol,
                     &As[buf][w * 512]);
        // B: 256 rows, 4 DMAs/thread
        #pragma unroll
        for (int u = 0; u < 4; ++u) {
            const int e0 = (w * 4 + u) * 512;
            async_copy16(Bw + (size_t)((e0 >> 5) + srow) * K + kt + scol,
                         &Bs[buf][e0]);
        }
    };

    stage(0, 0);

    for (int it = 0; it < NK; ++it) {
        __syncthreads();
        if (it + 1 < NK) stage((it + 1) & 1, (it + 1) << 5);

        const int buf = it & 1;
        const v8s af = *(const v8s*)&As[buf][(16 * w + l15) * 32 + quad * 8];
        #pragma unroll
        for (int j = 0; j < 16; ++j) {
            const v8s bfr = *(const v8s*)&Bs[buf][(16 * j + l15) * 32 + quad * 8];
            acc[j] = __builtin_amdgcn_mfma_f32_16x16x32_bf16(af, bfr, acc[j], 0, 0, 0);
        }
    }

    // ---- epilogue: bias + residual, then wave-local two-pass LN ----
    #pragma unroll
    for (int rr = 0; rr < 4; ++rr) {
        const int row = m0 + 16 * w + quad * 4 + rr;
        float v[16];
        float s = 0.f;
        #pragma unroll
        for (int j = 0; j < 16; ++j) {
            const int n = 16 * j + l15;
            v[j] = acc[j][rr] + biasv[n] + add[(size_t)row * CD + n];
            s += v[j];
        }
        #pragma unroll
        for (int off = 1; off < 16; off <<= 1) s += __shfl_xor(s, off);
        const float mean = s * (1.f / CD);
        float s2 = 0.f;
        #pragma unroll
        for (int j = 0; j < 16; ++j) { v[j] -= mean; s2 += v[j] * v[j]; }
        #pragma unroll
        for (int off = 1; off < 16; off <<= 1) s2 += __shfl_xor(s2, off);
        const float rstd = rsqrtf(s2 * (1.f / CD) + CEPS);
        #pragma unroll
        for (int j = 0; j < 16; ++j) {
            const int n = 16 * j + l15;
            const float y = v[j] * rstd * gw[n] + be[n];
            outf[(size_t)row * CD + n] = y;
            if (WRITE_BF) outb[(size_t)row * CD + n] = f2bf(y);
        }
    }
}

// ---------------------------------------------------------------------------
// Prep: adj->int8, src->bf16, weight transposes via 64x64 LDS tiles (both
// sides coalesced), biases packed.
// blocks: [0,8192) adj | [8192,10240) src | [10240,10480) transpose | 12 bias
// ---------------------------------------------------------------------------
__global__ __launch_bounds__(256)
void prep(const int* __restrict__ adj, const float* __restrict__ src,
          const float* __restrict__ Wq, const float* __restrict__ Wk,
          const float* __restrict__ Wv, const float* __restrict__ Wo,
          const float* __restrict__ W1, const float* __restrict__ W2,
          const float* __restrict__ bq, const float* __restrict__ bk,
          const float* __restrict__ bv, const float* __restrict__ bo,
          const float* __restrict__ b1, const float* __restrict__ b2,
          unsigned char* __restrict__ adj8, short* __restrict__ src_bf,
          short* __restrict__ wqkvT, short* __restrict__ woT,
          short* __restrict__ w1T, short* __restrict__ w2T,
          float* __restrict__ bpack)
{
    __shared__ float tile[64][65];
    const int bx = blockIdx.x, t = threadIdx.x;
    if (bx < 8192) {                                   // adj cast: 2M int4
        const int i = bx * 256 + t;
        const int4 vv = ((const int4*)adj)[i];
        uchar4 c;
        c.x = (unsigned char)vv.x; c.y = (unsigned char)vv.y;
        c.z = (unsigned char)vv.z; c.w = (unsigned char)vv.w;
        ((uchar4*)adj8)[i] = c;
    } else if (bx < 10240) {                           // src cast: 512K float4
        const int i = (bx - 8192) * 256 + t;
        const float4 v = ((const float4*)src)[i];
        short4 o;
        o.x = f2bf(v.x); o.y = f2bf(v.y); o.z = f2bf(v.z); o.w = f2bf(v.w);
        ((short4*)src_bf)[i] = o;
    } else if (bx < 10480) {                           // weight transposes
        const int tt = bx - 10240;
        const float* S; short* D;
        int Sstride, Dstride, k0, srccol, dstrow;
        if (tt < 96) {                                 // wqkv: 24x4 tiles
            const int tk = tt & 3, tn = tt >> 2;
            const int ng = tn * 64;
            Sstride = 256; Dstride = 256; k0 = tk * 64;
            dstrow = tn * 64; D = wqkvT;
            if (ng < 256)      { S = Wq; srccol = ng; }
            else if (ng < 512) { S = Wk; srccol = ng - 256; }
            else { const int r = (ng - 512) >> 8;
                   S = Wv + (size_t)r * 65536; srccol = (ng - 512) & 255; }
        } else if (tt < 112) {                         // wo: 4x4
            const int u = tt - 96, tk = u & 3, tn = u >> 2;
            S = Wo; Sstride = 256; D = woT; Dstride = 256;
            k0 = tk * 64; srccol = tn * 64; dstrow = tn * 64;
        } else if (tt < 176) {                         // w1: 16x4
            const int u = tt - 112, tk = u & 3, tn = u >> 2;
            S = W1; Sstride = 1024; D = w1T; Dstride = 256;
            k0 = tk * 64; srccol = tn * 64; dstrow = tn * 64;
        } else {                                       // w2: 4x16
            const int u = tt - 176, tk = u & 15, tn = u >> 4;
            S = W2; Sstride = 256; D = w2T; Dstride = 1024;
            k0 = tk * 64; srccol = tn * 64; dstrow = tn * 64;
        }
        #pragma unroll
        for (int u2 = 0; u2 < 4; ++u2) {               // coalesced read
            const int kl = (t >> 4) + u2 * 16;
            const int nl = (t & 15) * 4;
            const float4 v = *(const float4*)&S[(size_t)(k0 + kl) * Sstride + srccol + nl];
            tile[kl][nl + 0] = v.x; tile[kl][nl + 1] = v.y;
            tile[kl][nl + 2] = v.z; tile[kl][nl + 3] = v.w;
        }
        __syncthreads();
        #pragma unroll
        for (int u2 = 0; u2 < 4; ++u2) {               // coalesced write
            const int nl = (t >> 4) + u2 * 16;
            const int kl = (t & 15) * 4;
            short4 o;
            o.x = f2bf(tile[kl + 0][nl]); o.y = f2bf(tile[kl + 1][nl]);
            o.z = f2bf(tile[kl + 2][nl]); o.w = f2bf(tile[kl + 3][nl]);
            *(short4*)&D[(size_t)(dstrow + nl) * Dstride + k0 + kl] = o;
        }
    } else {                                           // biases: 3072
        const int idx = (bx - 10480) * 256 + t;
        float bvv;
        if (idx < 256)       bvv = bq[idx];
        else if (idx < 512)  bvv = bk[idx - 256];
        else if (idx < 1536) bvv = bv[idx - 512];
        else if (idx < 1792) bvv = bo[idx - 1536];
        else if (idx < 2816) bvv = b1[idx - 1792];
        else                 bvv = b2[idx - 2816];
        bpack[idx] = bvv;
    }
}

// ---------------------------------------------------------------------------
// Fused relational attention (UNCHANGED from round 6: ~69 us, proven).
// ---------------------------------------------------------------------------
__global__ __launch_bounds__(256)
void attn_mfma(const short* __restrict__ qg, const short* __restrict__ kg,
               const short* __restrict__ vt, const unsigned char* __restrict__ adj8,
               short* __restrict__ outh)
{
    __shared__ __align__(16) short ks[64 * 32];         // K tile [j][32], DMA
    __shared__ __align__(16) short vtile[4][32][72];    // V^T tiles [r][d][j]
    __shared__ __align__(16) short ps[64][68];          // P tile [i][j]
    __shared__ __align__(16) unsigned char adjs[64][72];// adj tile [i][j]
    __shared__ int lut[64][4];                          // byte-pair -> selectors

    const int t    = threadIdx.x;
    const int lane = t & 63;
    const int w    = t >> 6;          // wave 0..3
    const int quad = lane >> 4;
    const int l15  = lane & 15;
    const int i0   = blockIdx.x * 64;
    const int h    = blockIdx.y;
    const int b    = blockIdx.z;
    const int bhh  = b * CH + h;
    const size_t bh = (size_t)bhh;

    if (t < 64) {
        const int b0 = t & 7, b1 = t >> 3;
        #pragma unroll
        for (int r = 0; r < 4; ++r) {
            const int lo = (b0 == r) ? 0x0100 : 0x0c0c;
            const int hi = (b1 == r) ? 0x0302 : 0x0c0c;
            lut[t][r] = lo | (hi << 16);
        }
    }

    const v8s qfrag = *(const v8s*)&qg[(bh * CN + i0 + 16 * w + l15) * CDH + quad * 8];

    v4f oacc[2];
    oacc[0] = (v4f){0.f, 0.f, 0.f, 0.f};
    oacc[1] = (v4f){0.f, 0.f, 0.f, 0.f};
    float plsum[4] = {0.f, 0.f, 0.f, 0.f};

    const float cs = 0.25503480f;     // (1/sqrt(32)) * log2(e)
    const int arow = 16 * w + l15;    // this lane's P/adj row (wave-private)

    const int srow = lane >> 2;            // K: row within wave-issue
    const int scol = (lane & 3) * 8;       // K: 8-elem chunk
    const int vd0  = lane >> 3;            // V: base d (0..7), +8*it
    const int vc   = (lane & 7) * 8;       // V: j chunk
    const short* vplane = vt + (((size_t)(w * 64 + bhh)) * CDH) * CN;  // wave w -> relation w
    const int aro = t >> 2;                // adj: row
    const int aco = (t & 3) * 16;          // adj: 16B chunk

    for (int jt = 0; jt < 16; ++jt) {
        const int j0 = jt * 64;
        __syncthreads();              // previous tile fully consumed

        async_copy16(kg + (bh * CN + j0 + 16 * w + srow) * CDH + scol,
                     &ks[(16 * w + srow) * 32]);
        #pragma unroll
        for (int it = 0; it < 4; ++it) {
            const int d = vd0 + 8 * it;
            const v8s vv = *(const v8s*)&vplane[(size_t)d * CN + j0 + vc];
            *(v8s*)&vtile[w][d][vc] = vv;
        }
        const int4 av = *(const int4*)&adj8[((size_t)b * CN + i0 + aro) * CN + j0 + aco];
        *(int4*)&adjs[aro][aco] = av;
        __syncthreads();

        v4f sacc[4];
        #pragma unroll
        for (int jb = 0; jb < 4; ++jb) {
            const v8s kfrag = *(const v8s*)&ks[(16 * jb + l15) * 32 + quad * 8];
            sacc[jb] = __builtin_amdgcn_mfma_f32_16x16x32_bf16(
                qfrag, kfrag, (v4f){0.f, 0.f, 0.f, 0.f}, 0, 0, 0);
        }

        #pragma unroll
        for (int rr = 0; rr < 4; ++rr) {
            const int prow = 16 * w + quad * 4 + rr;
            float p[4];
            #pragma unroll
            for (int jb = 0; jb < 4; ++jb) p[jb] = exp2f(cs * sacc[jb][rr]);
            plsum[rr] += (p[0] + p[1]) + (p[2] + p[3]);
            #pragma unroll
            for (int jb = 0; jb < 4; ++jb)
                ps[prow][16 * jb + l15] = f2bf(p[jb]);
        }

        #pragma unroll
        for (int kb = 0; kb < 2; ++kb) {
            const int2 p0 = *(const int2*)&ps[arow][32 * kb + quad * 8];
            const int2 p1 = *(const int2*)&ps[arow][32 * kb + quad * 8 + 4];
            const int2 ab = *(const int2*)&adjs[arow][32 * kb + quad * 8];
            int pf[4][4];
            #pragma unroll
            for (int half = 0; half < 2; ++half) {
                const unsigned a = (unsigned)(half ? ab.y : ab.x);
                const int P0 = half ? p1.x : p0.x;
                const int P1 = half ? p1.y : p0.y;
                const int idxA = (a & 7) | ((a >> 5) & 0x38);
                const int idxB = ((a >> 16) & 7) | ((a >> 21) & 0x38);
                const int4 selA = *(const int4*)&lut[idxA][0];
                const int4 selB = *(const int4*)&lut[idxB][0];
                pf[0][half * 2 + 0] = __builtin_amdgcn_perm(P0, P0, selA.x);
                pf[1][half * 2 + 0] = __builtin_amdgcn_perm(P0, P0, selA.y);
                pf[2][half * 2 + 0] = __builtin_amdgcn_perm(P0, P0, selA.z);
                pf[3][half * 2 + 0] = __builtin_amdgcn_perm(P0, P0, selA.w);
                pf[0][half * 2 + 1] = __builtin_amdgcn_perm(P1, P1, selB.x);
                pf[1][half * 2 + 1] = __builtin_amdgcn_perm(P1, P1, selB.y);
                pf[2][half * 2 + 1] = __builtin_amdgcn_perm(P1, P1, selB.z);
                pf[3][half * 2 + 1] = __builtin_amdgcn_perm(P1, P1, selB.w);
            }
            #pragma unroll
            for (int r = 0; r < 4; ++r) {
                const v8s pfr = __builtin_bit_cast(v8s,
                    make_int4(pf[r][0], pf[r][1], pf[r][2], pf[r][3]));
                #pragma unroll
                for (int cb = 0; cb < 2; ++cb) {
                    const v8s vfrag = *(const v8s*)&vtile[r][16 * cb + l15][32 * kb + quad * 8];
                    oacc[cb] = __builtin_amdgcn_mfma_f32_16x16x32_bf16(
                        pfr, vfrag, oacc[cb], 0, 0, 0);
                }
            }
        }
    }

    #pragma unroll
    for (int rr = 0; rr < 4; ++rr) {
        float l = plsum[rr];
        #pragma unroll
        for (int off = 1; off < 16; off <<= 1) l += __shfl_xor(l, off);
        const float inv = 1.f / l;
        const int row = i0 + 16 * w + quad * 4 + rr;
        #pragma unroll
        for (int cb = 0; cb < 2; ++cb)
            outh[((size_t)b * CN + row) * CD + h * CDH + 16 * cb + l15] =
                f2bf(oacc[cb][rr] * inv);
    }
}

// ---------------------------------------------------------------------------
extern "C" void kernel_launch(void* const* d_in, const int* in_sizes, int n_in,
                              void* d_out, int out_size, void* d_ws, size_t ws_size,
                              hipStream_t stream)
{
    const float* src = (const float*)d_in[0];
    const int*   adj = (const int*)d_in[1];
    const float* Wq  = (const float*)d_in[2];
    const float* bq  = (const float*)d_in[3];
    const float* Wk  = (const float*)d_in[4];
    const float* bk  = (const float*)d_in[5];
    const float* Wv  = (const float*)d_in[6];
    const float* bv  = (const float*)d_in[7];
    const float* Wo  = (const float*)d_in[8];
    const float* bo  = (const float*)d_in[9];
    const float* W1  = (const float*)d_in[10];
    const float* b1  = (const float*)d_in[11];
    const float* W2  = (const float*)d_in[12];
    const float* b2  = (const float*)d_in[13];
    const float* g1  = (const float*)d_in[14];
    const float* be1 = (const float*)d_in[15];
    const float* g2  = (const float*)d_in[16];
    const float* be2 = (const float*)d_in[17];
    float* out = (float*)d_out;

    char* wsb = (char*)d_ws;
    const size_t MB = (size_t)1 << 20;

    // workspace layout (50 MB with aliasing)
    unsigned char* adj8 = (unsigned char*)(wsb);            // [0,8) MB
    short* qkv_bf = (short*)(wsb + 8 * MB);                 // [8,32): q,k planes + vT
    short* src_bf = (short*)(wsb + 32 * MB);                // [32,36)
    short* wqkvT  = (short*)(wsb + 36 * MB);                // 768 KB
    short* woT    = (short*)(wsb + 36 * MB + 768 * 1024);   // 128 KB
    short* w1T    = (short*)(wsb + 36 * MB + 896 * 1024);   // 512 KB
    short* w2T    = (short*)(wsb + 36 * MB + 1408 * 1024);  // 512 KB
    float* bpack  = (float*)(wsb + 36 * MB + 1920 * 1024);  // 12 KB
    short* heads_bf = (short*)(wsb + 38 * MB);              // [38,42)
    float* xres   = (float*)(wsb + 42 * MB);                // [42,50): LN1 fp32
    short* x_bf   = (short*)(wsb + 32 * MB);                // reuse src_bf
    short* h1_bf  = (short*)(wsb + 16 * MB);                // reuse vT (dead post-attn)

    const int M = CB * CN;        // 8192
    dim3 blk(256);

    // prep: adj cast, src cast, coalesced weight transposes, biases
    prep<<<dim3(10492), blk, 0, stream>>>(adj, src, Wq, Wk, Wv, Wo, W1, W2,
        bq, bk, bv, bo, b1, b2, adj8, src_bf, wqkvT, woT, w1T, w2T, bpack);

    // fused QK + V^T projection: 1536 blocks, dynamic LDS 24 KB
    proj_kernel<<<dim3(1536), blk, 24576, stream>>>(src_bf, wqkvT, bpack, qkv_bf);

    // fused relational MFMA attention -> bf16 heads
    attn_mfma<<<dim3(CN / 64, CH, CB), blk, 0, stream>>>(
        qkv_bf, qkv_bf + SZH, qkv_bf + 2 * SZH, adj8, heads_bf);

    // O-projection + bias + residual(src) + LN1 -> xres fp32 + x_bf bf16
    gemm_ln<true><<<dim3(M / 64), blk, 0, stream>>>(
        heads_bf, woT, bpack + 1536, src, g1, be1, xres, x_bf, CD);

    // FFN1: 1024 blocks
    gemm_mfma<64, 128, MODE_FFN1><<<dim3(M / 64, CFF / 128), blk, 24576, stream>>>(
        x_bf, w1T, bpack + 1792, h1_bf, M, CD, CFF);

    // FFN2 + bias + residual(xres) + LN2 -> out fp32
    gemm_ln<false><<<dim3(M / 64), blk, 0, stream>>>(
        h1_bf, w2T, bpack + 2816, xres, g2, be2, out, nullptr, CFF);
}

// Round 10
// 246.089 us; speedup vs baseline: 1.0369x; 1.0369x over previous
//
#include <hip/hip_runtime.h>
#include <hip/hip_bf16.h>
#include <cmath>

// Problem constants (fixed by the reference)
constexpr int CB  = 8;     // batch
constexpr int CN  = 1024;  // sequence length
constexpr int CD  = 256;   // model dim
constexpr int CH  = 8;     // heads
constexpr int CDH = 32;    // head dim
constexpr int CR  = 4;     // relation types (adj value 4 = none)
constexpr int CFF = 1024;  // ffn dim
constexpr float CEPS = 1e-5f;
constexpr size_t SZH = (size_t)CB * CH * CN * CDH;  // 2M: one head-plane

#define MODE_QK    0   // scatter bf16 q/k head-major planes, +bias (cols 0..511)
#define MODE_FFN1  2   // +bias, tanh-gelu -> bf16
#define MODE_VT    4   // V^T gemm (A=weight rows, B=src rows): coalesced store

typedef float v4f __attribute__((ext_vector_type(4)));
typedef short v8s __attribute__((ext_vector_type(8)));

static __device__ __forceinline__ short f2bf(float f) {
    unsigned u = __builtin_bit_cast(unsigned, f);
    u += 0x7fff + ((u >> 16) & 1);          // round-to-nearest-even
    return (short)(u >> 16);
}

static __device__ __forceinline__ void async_copy16(const void* g, void* l) {
    __builtin_amdgcn_global_load_lds(
        (const __attribute__((address_space(1))) void*)g,
        (__attribute__((address_space(3))) void*)l, 16, 0, 0);
}

// ---------------------------------------------------------------------------
// bf16 MFMA GEMM body (device fn, dynamic LDS): epilogue(A[M,K] @ Bw[N,K])
// BM x BN tile, 4 waves 2x2, BK=32 double-buffered 1-deep prefetch.
// ---------------------------------------------------------------------------
template<int BM, int BN, int MODE>
__device__ __forceinline__ void gemm_body(
    const short* __restrict__ A, const short* __restrict__ Bw,
    const float* __restrict__ biasv, void* __restrict__ dest,
    int M, int K, int Nw, int bx, int by, short* smem)
{
    constexpr int WTM = BM / 2, WTN = BN / 2;
    constexpr int TM = WTM / 16, TN = WTN / 16;
    short* As = smem;                    // [2][BM*32]
    short* Bs = smem + 2 * BM * 32;      // [2][BN*32]

    const int t    = threadIdx.x;
    const int lane = t & 63;
    const int w    = t >> 6;
    const int quad = lane >> 4, l15 = lane & 15;
    const int wm = w >> 1, wn = w & 1;
    const int m0 = bx * BM, n0 = by * BN;

    const int srow = lane >> 2;
    const int scol = (lane & 3) * 8;

    v4f acc[TM][TN];
    #pragma unroll
    for (int i = 0; i < TM; ++i)
        #pragma unroll
        for (int j = 0; j < TN; ++j) acc[i][j] = (v4f){0.f, 0.f, 0.f, 0.f};

    const int NK = K >> 5;

    auto stage = [&](int buf, int kt) {
        #pragma unroll
        for (int u = 0; u < BM / 64; ++u) {
            const int e0 = (w * (BM / 64) + u) * 512;
            const int row = (e0 >> 5) + srow;
            async_copy16(A + (size_t)(m0 + row) * K + kt + scol,
                         &As[buf * BM * 32 + e0]);
        }
        #pragma unroll
        for (int u = 0; u < BN / 64; ++u) {
            const int e0 = (w * (BN / 64) + u) * 512;
            const int row = (e0 >> 5) + srow;
            async_copy16(Bw + (size_t)(n0 + row) * K + kt + scol,
                         &Bs[buf * BN * 32 + e0]);
        }
    };

    stage(0, 0);

    for (int it = 0; it < NK; ++it) {
        __syncthreads();
        if (it + 1 < NK) stage((it + 1) & 1, (it + 1) << 5);

        const int buf = it & 1;
        v8s af[TM], bfr[TN];
        #pragma unroll
        for (int i = 0; i < TM; ++i)
            af[i] = *(const v8s*)&As[buf * BM * 32 +
                                     (wm * WTM + i * 16 + l15) * 32 + quad * 8];
        #pragma unroll
        for (int j = 0; j < TN; ++j)
            bfr[j] = *(const v8s*)&Bs[buf * BN * 32 +
                                      (wn * WTN + j * 16 + l15) * 32 + quad * 8];
        #pragma unroll
        for (int i = 0; i < TM; ++i)
            #pragma unroll
            for (int j = 0; j < TN; ++j)
                acc[i][j] = __builtin_amdgcn_mfma_f32_16x16x32_bf16(
                    af[i], bfr[j], acc[i][j], 0, 0, 0);
    }

    #pragma unroll
    for (int i = 0; i < TM; ++i) {
        #pragma unroll
        for (int j = 0; j < TN; ++j) {
            const int mb = m0 + wm * WTM + i * 16 + quad * 4;   // row of rr=0
            const int n  = n0 + wn * WTN + j * 16 + l15;
            float vals[4];
            if (MODE == MODE_VT) {
                #pragma unroll
                for (int rr = 0; rr < 4; ++rr) vals[rr] = acc[i][j][rr] + biasv[mb + rr];
            } else {
                #pragma unroll
                for (int rr = 0; rr < 4; ++rr) vals[rr] = acc[i][j][rr] + biasv[n];
            }

            if (MODE == MODE_QK) {
                const int b = mb >> 10, ii0 = mb & 1023;
                const int plane = n >> 8, nn = n & 255;
                const int h = nn >> 5, d = nn & 31;
                #pragma unroll
                for (int rr = 0; rr < 4; ++rr)
                    ((short*)dest)[(size_t)plane * SZH +
                        (((size_t)(b * CH + h)) * CN + ii0 + rr) * CDH + d] =
                        f2bf(vals[rr]);
            } else if (MODE == MODE_VT) {
                const int b = n >> 10, ii = n & 1023;
                #pragma unroll
                for (int rr = 0; rr < 4; ++rr) {
                    const int m = mb + rr;
                    const int r2 = m >> 8, hd = m & 255;
                    const int h = hd >> 5, d = hd & 31;
                    ((short*)dest)[2 * SZH +
                        (((size_t)(r2 * 64 + b * CH + h)) * CDH + d) * CN + ii] =
                        f2bf(vals[rr]);
                }
            } else { // MODE_FFN1: tanh-gelu -> bf16 (x*E/(E+1))
                #pragma unroll
                for (int rr = 0; rr < 4; ++rr) {
                    const size_t idx = (size_t)(mb + rr) * Nw + n;
                    const float xx = vals[rr];
                    const float E = exp2f(2.302217f * (xx + 0.044715f * xx * xx * xx));
                    ((short*)dest)[idx] = f2bf(xx * E / (E + 1.f));
                }
            }
        }
    }
}

template<int BM, int BN, int MODE>
__global__ __launch_bounds__(256)
void gemm_mfma(const short* __restrict__ A, const short* __restrict__ Bw,
               const float* __restrict__ biasv, void* __restrict__ dest,
               int M, int K, int Nw)
{
    extern __shared__ short smem[];
    gemm_body<BM, BN, MODE>(A, Bw, biasv, dest, M, K, Nw,
                            blockIdx.x, blockIdx.y, smem);
}

// ---------------------------------------------------------------------------
// Fused projection dispatch: blocks 0..511 = QK (8192x512), 512..1535 = V^T,
// 1536..2047 = adj int32->int8 cast (grid-stride; no dependency on GEMM out,
// rides along to hide its memcpy behind MFMA work).
// ---------------------------------------------------------------------------
__global__ __launch_bounds__(256)
void proj_kernel(const short* __restrict__ src_bf, const short* __restrict__ wqkvT,
                 const float* __restrict__ bpack, short* __restrict__ qkv,
                 const int* __restrict__ adj, unsigned char* __restrict__ adj8)
{
    extern __shared__ short smem[];
    const int g = blockIdx.x;
    if (g < 512) {
        gemm_body<64, 128, MODE_QK>(src_bf, wqkvT, bpack, qkv,
                                    8192, 256, 512, g >> 2, g & 3, smem);
    } else if (g < 1536) {
        const int h2 = g - 512;
        gemm_body<64, 128, MODE_VT>(wqkvT + 512 * 256, src_bf, bpack + 512,
                                    qkv, 1024, 256, 8192, h2 & 15, h2 >> 4, smem);
    } else {
        const int n4 = CB * CN * CN / 4;             // 2M int4 groups
        for (int i = (g - 1536) * 256 + threadIdx.x; i < n4; i += 512 * 256) {
            const int4 vv = ((const int4*)adj)[i];
            uchar4 c;
            c.x = (unsigned char)vv.x; c.y = (unsigned char)vv.y;
            c.z = (unsigned char)vv.z; c.w = (unsigned char)vv.w;
            ((uchar4*)adj8)[i] = c;
        }
    }
}

// ---------------------------------------------------------------------------
// FUSED GEMM + bias + residual + LayerNorm, BM=32 -> 256 blocks (1/CU).
// 4 waves = 2 row-groups x 2 column-halves; each wave: 16 rows x 128 cols
// (8 MFMA/iter).  LN stats combined across the two column halves via LDS
// (single-pass moments).  outf fp32 always; outb bf16 optional.
// ---------------------------------------------------------------------------
template<bool WRITE_BF>
__global__ __launch_bounds__(256)
void gemm_ln32(const short* __restrict__ A, const short* __restrict__ Bw,
               const float* __restrict__ biasv, const float* __restrict__ add,
               const float* __restrict__ gw, const float* __restrict__ be,
               float* __restrict__ outf, short* __restrict__ outb, int K)
{
    __shared__ short As[2][32 * 32];
    __shared__ short Bs[2][256 * 32];
    __shared__ float redS[2][16][2], redQ[2][16][2];

    const int t    = threadIdx.x;
    const int lane = t & 63;
    const int w    = t >> 6;
    const int quad = lane >> 4, l15 = lane & 15;
    const int wr   = w >> 1;          // row group: rows 16*wr .. 16*wr+15
    const int wg   = w & 1;           // column half: cols wg*128 .. +128
    const int m0   = blockIdx.x * 32;

    const int srow = lane >> 2;
    const int scol = (lane & 3) * 8;

    v4f acc[8];
    #pragma unroll
    for (int j = 0; j < 8; ++j) acc[j] = (v4f){0.f, 0.f, 0.f, 0.f};

    const int NK = K >> 5;

    auto stage = [&](int buf, int kt) {
        if (w < 2)   // A: 32 rows, waves 0,1 (wave-uniform base + lane*16B)
            async_copy16(A + (size_t)(m0 + 16 * w + srow) * K + kt + scol,
                         &As[buf][w * 512]);
        #pragma unroll
        for (int u = 0; u < 4; ++u) {   // B: 256 rows, 4 DMAs/thread
            const int e0 = (w * 4 + u) * 512;
            async_copy16(Bw + (size_t)((e0 >> 5) + srow) * K + kt + scol,
                         &Bs[buf][e0]);
        }
    };

    stage(0, 0);

    for (int it = 0; it < NK; ++it) {
        __syncthreads();
        if (it + 1 < NK) stage((it + 1) & 1, (it + 1) << 5);

        const int buf = it & 1;
        const v8s af = *(const v8s*)&As[buf][(16 * wr + l15) * 32 + quad * 8];
        #pragma unroll
        for (int j = 0; j < 8; ++j) {
            const v8s bfr = *(const v8s*)&Bs[buf][(wg * 128 + 16 * j + l15) * 32 + quad * 8];
            acc[j] = __builtin_amdgcn_mfma_f32_16x16x32_bf16(af, bfr, acc[j], 0, 0, 0);
        }
    }

    // ---- epilogue: bias + residual; per-row moments over this col-half ----
    float v[4][8];
    #pragma unroll
    for (int rr = 0; rr < 4; ++rr) {
        const int row = m0 + 16 * wr + quad * 4 + rr;
        float s = 0.f, sq = 0.f;
        #pragma unroll
        for (int j = 0; j < 8; ++j) {
            const int n = wg * 128 + 16 * j + l15;
            const float x = acc[j][rr] + biasv[n] + add[(size_t)row * CD + n];
            v[rr][j] = x;
            s += x; sq += x * x;
        }
        #pragma unroll
        for (int off = 1; off < 16; off <<= 1) {
            s  += __shfl_xor(s, off);
            sq += __shfl_xor(sq, off);
        }
        if (l15 == 0) {
            redS[wr][quad * 4 + rr][wg] = s;
            redQ[wr][quad * 4 + rr][wg] = sq;
        }
    }
    __syncthreads();

    #pragma unroll
    for (int rr = 0; rr < 4; ++rr) {
        const int r16 = quad * 4 + rr;
        const int row = m0 + 16 * wr + r16;
        const float s  = redS[wr][r16][0] + redS[wr][r16][1];
        const float sq = redQ[wr][r16][0] + redQ[wr][r16][1];
        const float mean = s * (1.f / CD);
        const float var  = sq * (1.f / CD) - mean * mean;
        const float rstd = rsqrtf(var + CEPS);
        #pragma unroll
        for (int j = 0; j < 8; ++j) {
            const int n = wg * 128 + 16 * j + l15;
            const float y = (v[rr][j] - mean) * rstd * gw[n] + be[n];
            outf[(size_t)row * CD + n] = y;
            if (WRITE_BF) outb[(size_t)row * CD + n] = f2bf(y);
        }
    }
}

// ---------------------------------------------------------------------------
// Prep: src->bf16, weight transposes via 64x64 LDS tiles, biases packed.
// blocks: [0,2048) src | [2048,2288) transpose | [2288,2300) bias
// ---------------------------------------------------------------------------
__global__ __launch_bounds__(256)
void prep(const float* __restrict__ src,
          const float* __restrict__ Wq, const float* __restrict__ Wk,
          const float* __restrict__ Wv, const float* __restrict__ Wo,
          const float* __restrict__ W1, const float* __restrict__ W2,
          const float* __restrict__ bq, const float* __restrict__ bk,
          const float* __restrict__ bv, const float* __restrict__ bo,
          const float* __restrict__ b1, const float* __restrict__ b2,
          short* __restrict__ src_bf,
          short* __restrict__ wqkvT, short* __restrict__ woT,
          short* __restrict__ w1T, short* __restrict__ w2T,
          float* __restrict__ bpack)
{
    __shared__ float tile[64][65];
    const int bx = blockIdx.x, t = threadIdx.x;
    if (bx < 2048) {                                   // src cast: 512K float4
        const int i = bx * 256 + t;
        const float4 v = ((const float4*)src)[i];
        short4 o;
        o.x = f2bf(v.x); o.y = f2bf(v.y); o.z = f2bf(v.z); o.w = f2bf(v.w);
        ((short4*)src_bf)[i] = o;
    } else if (bx < 2288) {                            // weight transposes
        const int tt = bx - 2048;
        const float* S; short* D;
        int Sstride, Dstride, k0, srccol, dstrow;
        if (tt < 96) {                                 // wqkv: 24x4 tiles
            const int tk = tt & 3, tn = tt >> 2;
            const int ng = tn * 64;
            Sstride = 256; Dstride = 256; k0 = tk * 64;
            dstrow = tn * 64; D = wqkvT;
            if (ng < 256)      { S = Wq; srccol = ng; }
            else if (ng < 512) { S = Wk; srccol = ng - 256; }
            else { const int r = (ng - 512) >> 8;
                   S = Wv + (size_t)r * 65536; srccol = (ng - 512) & 255; }
        } else if (tt < 112) {                         // wo: 4x4
            const int u = tt - 96, tk = u & 3, tn = u >> 2;
            S = Wo; Sstride = 256; D = woT; Dstride = 256;
            k0 = tk * 64; srccol = tn * 64; dstrow = tn * 64;
        } else if (tt < 176) {                         // w1: 16x4
            const int u = tt - 112, tk = u & 3, tn = u >> 2;
            S = W1; Sstride = 1024; D = w1T; Dstride = 256;
            k0 = tk * 64; srccol = tn * 64; dstrow = tn * 64;
        } else {                                       // w2: 4x16
            const int u = tt - 176, tk = u & 15, tn = u >> 4;
            S = W2; Sstride = 256; D = w2T; Dstride = 1024;
            k0 = tk * 64; srccol = tn * 64; dstrow = tn * 64;
        }
        #pragma unroll
        for (int u2 = 0; u2 < 4; ++u2) {               // coalesced read
            const int kl = (t >> 4) + u2 * 16;
            const int nl = (t & 15) * 4;
            const float4 v = *(const float4*)&S[(size_t)(k0 + kl) * Sstride + srccol + nl];
            tile[kl][nl + 0] = v.x; tile[kl][nl + 1] = v.y;
            tile[kl][nl + 2] = v.z; tile[kl][nl + 3] = v.w;
        }
        __syncthreads();
        #pragma unroll
        for (int u2 = 0; u2 < 4; ++u2) {               // coalesced write
            const int nl = (t >> 4) + u2 * 16;
            const int kl = (t & 15) * 4;
            short4 o;
            o.x = f2bf(tile[kl + 0][nl]); o.y = f2bf(tile[kl + 1][nl]);
            o.z = f2bf(tile[kl + 2][nl]); o.w = f2bf(tile[kl + 3][nl]);
            *(short4*)&D[(size_t)(dstrow + nl) * Dstride + k0 + kl] = o;
        }
    } else {                                           // biases: 3072
        const int idx = (bx - 2288) * 256 + t;
        float bvv;
        if (idx < 256)       bvv = bq[idx];
        else if (idx < 512)  bvv = bk[idx - 256];
        else if (idx < 1536) bvv = bv[idx - 512];
        else if (idx < 1792) bvv = bo[idx - 1536];
        else if (idx < 2816) bvv = b1[idx - 1792];
        else                 bvv = b2[idx - 2816];
        bpack[idx] = bvv;
    }
}

// ---------------------------------------------------------------------------
// Fused relational attention (UNCHANGED from round 6: ~69 us, proven).
// ---------------------------------------------------------------------------
__global__ __launch_bounds__(256)
void attn_mfma(const short* __restrict__ qg, const short* __restrict__ kg,
               const short* __restrict__ vt, const unsigned char* __restrict__ adj8,
               short* __restrict__ outh)
{
    __shared__ __align__(16) short ks[64 * 32];         // K tile [j][32], DMA
    __shared__ __align__(16) short vtile[4][32][72];    // V^T tiles [r][d][j]
    __shared__ __align__(16) short ps[64][68];          // P tile [i][j]
    __shared__ __align__(16) unsigned char adjs[64][72];// adj tile [i][j]
    __shared__ int lut[64][4];                          // byte-pair -> selectors

    const int t    = threadIdx.x;
    const int lane = t & 63;
    const int w    = t >> 6;          // wave 0..3
    const int quad = lane >> 4;
    const int l15  = lane & 15;
    const int i0   = blockIdx.x * 64;
    const int h    = blockIdx.y;
    const int b    = blockIdx.z;
    const int bhh  = b * CH + h;
    const size_t bh = (size_t)bhh;

    if (t < 64) {
        const int b0 = t & 7, b1 = t >> 3;
        #pragma unroll
        for (int r = 0; r < 4; ++r) {
            const int lo = (b0 == r) ? 0x0100 : 0x0c0c;
            const int hi = (b1 == r) ? 0x0302 : 0x0c0c;
            lut[t][r] = lo | (hi << 16);
        }
    }

    const v8s qfrag = *(const v8s*)&qg[(bh * CN + i0 + 16 * w + l15) * CDH + quad * 8];

    v4f oacc[2];
    oacc[0] = (v4f){0.f, 0.f, 0.f, 0.f};
    oacc[1] = (v4f){0.f, 0.f, 0.f, 0.f};
    float plsum[4] = {0.f, 0.f, 0.f, 0.f};

    const float cs = 0.25503480f;     // (1/sqrt(32)) * log2(e)
    const int arow = 16 * w + l15;    // this lane's P/adj row (wave-private)

    const int srow = lane >> 2;            // K: row within wave-issue
    const int scol = (lane & 3) * 8;       // K: 8-elem chunk
    const int vd0  = lane >> 3;            // V: base d (0..7), +8*it
    const int vc   = (lane & 7) * 8;       // V: j chunk
    const short* vplane = vt + (((size_t)(w * 64 + bhh)) * CDH) * CN;  // wave w -> relation w
    const int aro = t >> 2;                // adj: row
    const int aco = (t & 3) * 16;          // adj: 16B chunk

    for (int jt = 0; jt < 16; ++jt) {
        const int j0 = jt * 64;
        __syncthreads();              // previous tile fully consumed

        async_copy16(kg + (bh * CN + j0 + 16 * w + srow) * CDH + scol,
                     &ks[(16 * w + srow) * 32]);
        #pragma unroll
        for (int it = 0; it < 4; ++it) {
            const int d = vd0 + 8 * it;
            const v8s vv = *(const v8s*)&vplane[(size_t)d * CN + j0 + vc];
            *(v8s*)&vtile[w][d][vc] = vv;
        }
        const int4 av = *(const int4*)&adj8[((size_t)b * CN + i0 + aro) * CN + j0 + aco];
        *(int4*)&adjs[aro][aco] = av;
        __syncthreads();

        v4f sacc[4];
        #pragma unroll
        for (int jb = 0; jb < 4; ++jb) {
            const v8s kfrag = *(const v8s*)&ks[(16 * jb + l15) * 32 + quad * 8];
            sacc[jb] = __builtin_amdgcn_mfma_f32_16x16x32_bf16(
                qfrag, kfrag, (v4f){0.f, 0.f, 0.f, 0.f}, 0, 0, 0);
        }

        #pragma unroll
        for (int rr = 0; rr < 4; ++rr) {
            const int prow = 16 * w + quad * 4 + rr;
            float p[4];
            #pragma unroll
            for (int jb = 0; jb < 4; ++jb) p[jb] = exp2f(cs * sacc[jb][rr]);
            plsum[rr] += (p[0] + p[1]) + (p[2] + p[3]);
            #pragma unroll
            for (int jb = 0; jb < 4; ++jb)
                ps[prow][16 * jb + l15] = f2bf(p[jb]);
        }

        #pragma unroll
        for (int kb = 0; kb < 2; ++kb) {
            const int2 p0 = *(const int2*)&ps[arow][32 * kb + quad * 8];
            const int2 p1 = *(const int2*)&ps[arow][32 * kb + quad * 8 + 4];
            const int2 ab = *(const int2*)&adjs[arow][32 * kb + quad * 8];
            int pf[4][4];
            #pragma unroll
            for (int half = 0; half < 2; ++half) {
                const unsigned a = (unsigned)(half ? ab.y : ab.x);
                const int P0 = half ? p1.x : p0.x;
                const int P1 = half ? p1.y : p0.y;
                const int idxA = (a & 7) | ((a >> 5) & 0x38);
                const int idxB = ((a >> 16) & 7) | ((a >> 21) & 0x38);
                const int4 selA = *(const int4*)&lut[idxA][0];
                const int4 selB = *(const int4*)&lut[idxB][0];
                pf[0][half * 2 + 0] = __builtin_amdgcn_perm(P0, P0, selA.x);
                pf[1][half * 2 + 0] = __builtin_amdgcn_perm(P0, P0, selA.y);
                pf[2][half * 2 + 0] = __builtin_amdgcn_perm(P0, P0, selA.z);
                pf[3][half * 2 + 0] = __builtin_amdgcn_perm(P0, P0, selA.w);
                pf[0][half * 2 + 1] = __builtin_amdgcn_perm(P1, P1, selB.x);
                pf[1][half * 2 + 1] = __builtin_amdgcn_perm(P1, P1, selB.y);
                pf[2][half * 2 + 1] = __builtin_amdgcn_perm(P1, P1, selB.z);
                pf[3][half * 2 + 1] = __builtin_amdgcn_perm(P1, P1, selB.w);
            }
            #pragma unroll
            for (int r = 0; r < 4; ++r) {
                const v8s pfr = __builtin_bit_cast(v8s,
                    make_int4(pf[r][0], pf[r][1], pf[r][2], pf[r][3]));
                #pragma unroll
                for (int cb = 0; cb < 2; ++cb) {
                    const v8s vfrag = *(const v8s*)&vtile[r][16 * cb + l15][32 * kb + quad * 8];
                    oacc[cb] = __builtin_amdgcn_mfma_f32_16x16x32_bf16(
                        pfr, vfrag, oacc[cb], 0, 0, 0);
                }
            }
        }
    }

    #pragma unroll
    for (int rr = 0; rr < 4; ++rr) {
        float l = plsum[rr];
        #pragma unroll
        for (int off = 1; off < 16; off <<= 1) l += __shfl_xor(l, off);
        const float inv = 1.f / l;
        const int row = i0 + 16 * w + quad * 4 + rr;
        #pragma unroll
        for (int cb = 0; cb < 2; ++cb)
            outh[((size_t)b * CN + row) * CD + h * CDH + 16 * cb + l15] =
                f2bf(oacc[cb][rr] * inv);
    }
}

// ---------------------------------------------------------------------------
extern "C" void kernel_launch(void* const* d_in, const int* in_sizes, int n_in,
                              void* d_out, int out_size, void* d_ws, size_t ws_size,
                              hipStream_t stream)
{
    const float* src = (const float*)d_in[0];
    const int*   adj = (const int*)d_in[1];
    const float* Wq  = (const float*)d_in[2];
    const float* bq  = (const float*)d_in[3];
    const float* Wk  = (const float*)d_in[4];
    const float* bk  = (const float*)d_in[5];
    const float* Wv  = (const float*)d_in[6];
    const float* bv  = (const float*)d_in[7];
    const float* Wo  = (const float*)d_in[8];
    const float* bo  = (const float*)d_in[9];
    const float* W1  = (const float*)d_in[10];
    const float* b1  = (const float*)d_in[11];
    const float* W2  = (const float*)d_in[12];
    const float* b2  = (const float*)d_in[13];
    const float* g1  = (const float*)d_in[14];
    const float* be1 = (const float*)d_in[15];
    const float* g2  = (const float*)d_in[16];
    const float* be2 = (const float*)d_in[17];
    float* out = (float*)d_out;

    char* wsb = (char*)d_ws;
    const size_t MB = (size_t)1 << 20;

    // workspace layout (50 MB with aliasing)
    unsigned char* adj8 = (unsigned char*)(wsb);            // [0,8) MB
    short* qkv_bf = (short*)(wsb + 8 * MB);                 // [8,32): q,k planes + vT
    short* src_bf = (short*)(wsb + 32 * MB);                // [32,36)
    short* wqkvT  = (short*)(wsb + 36 * MB);                // 768 KB
    short* woT    = (short*)(wsb + 36 * MB + 768 * 1024);   // 128 KB
    short* w1T    = (short*)(wsb + 36 * MB + 896 * 1024);   // 512 KB
    short* w2T    = (short*)(wsb + 36 * MB + 1408 * 1024);  // 512 KB
    float* bpack  = (float*)(wsb + 36 * MB + 1920 * 1024);  // 12 KB
    short* heads_bf = (short*)(wsb + 38 * MB);              // [38,42)
    float* xres   = (float*)(wsb + 42 * MB);                // [42,50): LN1 fp32
    short* x_bf   = (short*)(wsb + 32 * MB);                // reuse src_bf
    short* h1_bf  = (short*)(wsb + 16 * MB);                // reuse vT (dead post-attn)

    const int M = CB * CN;        // 8192
    dim3 blk(256);

    // prep: src cast, coalesced weight transposes, biases (2300 blocks)
    prep<<<dim3(2300), blk, 0, stream>>>(src, Wq, Wk, Wv, Wo, W1, W2,
        bq, bk, bv, bo, b1, b2, src_bf, wqkvT, woT, w1T, w2T, bpack);

    // fused QK + V^T projection + adj cast: 2048 blocks, dynamic LDS 24 KB
    proj_kernel<<<dim3(2048), blk, 24576, stream>>>(
        src_bf, wqkvT, bpack, qkv_bf, adj, adj8);

    // fused relational MFMA attention -> bf16 heads
    attn_mfma<<<dim3(CN / 64, CH, CB), blk, 0, stream>>>(
        qkv_bf, qkv_bf + SZH, qkv_bf + 2 * SZH, adj8, heads_bf);

    // O-projection + bias + residual(src) + LN1 -> xres fp32 + x_bf bf16
    gemm_ln32<true><<<dim3(M / 32), blk, 0, stream>>>(
        heads_bf, woT, bpack + 1536, src, g1, be1, xres, x_bf, CD);

    // FFN1: 1024 blocks
    gemm_mfma<64, 128, MODE_FFN1><<<dim3(M / 64, CFF / 128), blk, 24576, stream>>>(
        x_bf, w1T, bpack + 1792, h1_bf, M, CD, CFF);

    // FFN2 + bias + residual(xres) + LN2 -> out fp32
    gemm_ln32<false><<<dim3(M / 32), blk, 0, stream>>>(
        h1_bf, w2T, bpack + 2816, xres, g2, be2, out, nullptr, CFF);
}

// Round 11
// 238.138 us; speedup vs baseline: 1.0715x; 1.0334x over previous
//
#include <hip/hip_runtime.h>
#include <hip/hip_bf16.h>
#include <cmath>

// Problem constants (fixed by the reference)
constexpr int CB  = 8;     // batch
constexpr int CN  = 1024;  // sequence length
constexpr int CD  = 256;   // model dim
constexpr int CH  = 8;     // heads
constexpr int CDH = 32;    // head dim
constexpr int CR  = 4;     // relation types (adj value 4 = none)
constexpr int CFF = 1024;  // ffn dim
constexpr float CEPS = 1e-5f;
constexpr size_t SZH = (size_t)CB * CH * CN * CDH;  // 2M: one head-plane

#define MODE_QK    0   // scatter bf16 q/k head-major planes, +bias (cols 0..511)
#define MODE_FFN1  2   // +bias, tanh-gelu -> bf16
#define MODE_VT    4   // V^T gemm (A=weight rows, B=src rows): coalesced store

typedef float v4f __attribute__((ext_vector_type(4)));
typedef short v8s __attribute__((ext_vector_type(8)));

static __device__ __forceinline__ short f2bf(float f) {
    unsigned u = __builtin_bit_cast(unsigned, f);
    u += 0x7fff + ((u >> 16) & 1);          // round-to-nearest-even
    return (short)(u >> 16);
}

static __device__ __forceinline__ void async_copy16(const void* g, void* l) {
    __builtin_amdgcn_global_load_lds(
        (const __attribute__((address_space(1))) void*)g,
        (__attribute__((address_space(3))) void*)l, 16, 0, 0);
}

// ---------------------------------------------------------------------------
// bf16 MFMA GEMM body (device fn, dynamic LDS): epilogue(A[M,K] @ Bw[N,K])
// BM x BN tile, 4 waves 2x2, BK=32 double-buffered 1-deep prefetch.
// ---------------------------------------------------------------------------
template<int BM, int BN, int MODE>
__device__ __forceinline__ void gemm_body(
    const short* __restrict__ A, const short* __restrict__ Bw,
    const float* __restrict__ biasv, void* __restrict__ dest,
    int M, int K, int Nw, int bx, int by, short* smem)
{
    constexpr int WTM = BM / 2, WTN = BN / 2;
    constexpr int TM = WTM / 16, TN = WTN / 16;
    short* As = smem;                    // [2][BM*32]
    short* Bs = smem + 2 * BM * 32;      // [2][BN*32]

    const int t    = threadIdx.x;
    const int lane = t & 63;
    const int w    = t >> 6;
    const int quad = lane >> 4, l15 = lane & 15;
    const int wm = w >> 1, wn = w & 1;
    const int m0 = bx * BM, n0 = by * BN;

    const int srow = lane >> 2;
    const int scol = (lane & 3) * 8;

    v4f acc[TM][TN];
    #pragma unroll
    for (int i = 0; i < TM; ++i)
        #pragma unroll
        for (int j = 0; j < TN; ++j) acc[i][j] = (v4f){0.f, 0.f, 0.f, 0.f};

    const int NK = K >> 5;

    auto stage = [&](int buf, int kt) {
        #pragma unroll
        for (int u = 0; u < BM / 64; ++u) {
            const int e0 = (w * (BM / 64) + u) * 512;
            const int row = (e0 >> 5) + srow;
            async_copy16(A + (size_t)(m0 + row) * K + kt + scol,
                         &As[buf * BM * 32 + e0]);
        }
        #pragma unroll
        for (int u = 0; u < BN / 64; ++u) {
            const int e0 = (w * (BN / 64) + u) * 512;
            const int row = (e0 >> 5) + srow;
            async_copy16(Bw + (size_t)(n0 + row) * K + kt + scol,
                         &Bs[buf * BN * 32 + e0]);
        }
    };

    stage(0, 0);

    for (int it = 0; it < NK; ++it) {
        __syncthreads();
        if (it + 1 < NK) stage((it + 1) & 1, (it + 1) << 5);

        const int buf = it & 1;
        v8s af[TM], bfr[TN];
        #pragma unroll
        for (int i = 0; i < TM; ++i)
            af[i] = *(const v8s*)&As[buf * BM * 32 +
                                     (wm * WTM + i * 16 + l15) * 32 + quad * 8];
        #pragma unroll
        for (int j = 0; j < TN; ++j)
            bfr[j] = *(const v8s*)&Bs[buf * BN * 32 +
                                      (wn * WTN + j * 16 + l15) * 32 + quad * 8];
        #pragma unroll
        for (int i = 0; i < TM; ++i)
            #pragma unroll
            for (int j = 0; j < TN; ++j)
                acc[i][j] = __builtin_amdgcn_mfma_f32_16x16x32_bf16(
                    af[i], bfr[j], acc[i][j], 0, 0, 0);
    }

    #pragma unroll
    for (int i = 0; i < TM; ++i) {
        #pragma unroll
        for (int j = 0; j < TN; ++j) {
            const int mb = m0 + wm * WTM + i * 16 + quad * 4;   // row of rr=0
            const int n  = n0 + wn * WTN + j * 16 + l15;
            float vals[4];
            if (MODE == MODE_VT) {
                #pragma unroll
                for (int rr = 0; rr < 4; ++rr) vals[rr] = acc[i][j][rr] + biasv[mb + rr];
            } else {
                #pragma unroll
                for (int rr = 0; rr < 4; ++rr) vals[rr] = acc[i][j][rr] + biasv[n];
            }

            if (MODE == MODE_QK) {
                const int b = mb >> 10, ii0 = mb & 1023;
                const int plane = n >> 8, nn = n & 255;
                const int h = nn >> 5, d = nn & 31;
                #pragma unroll
                for (int rr = 0; rr < 4; ++rr)
                    ((short*)dest)[(size_t)plane * SZH +
                        (((size_t)(b * CH + h)) * CN + ii0 + rr) * CDH + d] =
                        f2bf(vals[rr]);
            } else if (MODE == MODE_VT) {
                const int b = n >> 10, ii = n & 1023;
                #pragma unroll
                for (int rr = 0; rr < 4; ++rr) {
                    const int m = mb + rr;
                    const int r2 = m >> 8, hd = m & 255;
                    const int h = hd >> 5, d = hd & 31;
                    ((short*)dest)[2 * SZH +
                        (((size_t)(r2 * 64 + b * CH + h)) * CDH + d) * CN + ii] =
                        f2bf(vals[rr]);
                }
            } else { // MODE_FFN1: tanh-gelu -> bf16 (x*E/(E+1))
                #pragma unroll
                for (int rr = 0; rr < 4; ++rr) {
                    const size_t idx = (size_t)(mb + rr) * Nw + n;
                    const float xx = vals[rr];
                    const float E = exp2f(2.302217f * (xx + 0.044715f * xx * xx * xx));
                    ((short*)dest)[idx] = f2bf(xx * E / (E + 1.f));
                }
            }
        }
    }
}

template<int BM, int BN, int MODE>
__global__ __launch_bounds__(256)
void gemm_mfma(const short* __restrict__ A, const short* __restrict__ Bw,
               const float* __restrict__ biasv, void* __restrict__ dest,
               int M, int K, int Nw)
{
    extern __shared__ short smem[];
    gemm_body<BM, BN, MODE>(A, Bw, biasv, dest, M, K, Nw,
                            blockIdx.x, blockIdx.y, smem);
}

// ---------------------------------------------------------------------------
// Fused projection dispatch: blocks 0..511 = QK (8192x512), 512..1535 = V^T,
// 1536..2047 = adj int32 -> 4-BIT pack (2 values/byte; values 0..4 fit).
// ---------------------------------------------------------------------------
__global__ __launch_bounds__(256)
void proj_kernel(const short* __restrict__ src_bf, const short* __restrict__ wqkvT,
                 const float* __restrict__ bpack, short* __restrict__ qkv,
                 const int* __restrict__ adj, unsigned char* __restrict__ adj4)
{
    extern __shared__ short smem[];
    const int g = blockIdx.x;
    if (g < 512) {
        gemm_body<64, 128, MODE_QK>(src_bf, wqkvT, bpack, qkv,
                                    8192, 256, 512, g >> 2, g & 3, smem);
    } else if (g < 1536) {
        const int h2 = g - 512;
        gemm_body<64, 128, MODE_VT>(wqkvT + 512 * 256, src_bf, bpack + 512,
                                    qkv, 1024, 256, 8192, h2 & 15, h2 >> 4, smem);
    } else {
        const int nout = CB * CN * CN / 8;           // 1M uints (8 values each)
        for (int i = (g - 1536) * 256 + threadIdx.x; i < nout; i += 512 * 256) {
            const int4 a0 = ((const int4*)adj)[2 * i];
            const int4 a1 = ((const int4*)adj)[2 * i + 1];
            const unsigned p =
                (unsigned)(a0.x & 0xf)        | ((unsigned)(a0.y & 0xf) << 4)  |
                ((unsigned)(a0.z & 0xf) << 8) | ((unsigned)(a0.w & 0xf) << 12) |
                ((unsigned)(a1.x & 0xf) << 16)| ((unsigned)(a1.y & 0xf) << 20) |
                ((unsigned)(a1.z & 0xf) << 24)| ((unsigned)(a1.w & 0xf) << 28);
            ((unsigned*)adj4)[i] = p;
        }
    }
}

// ---------------------------------------------------------------------------
// FUSED GEMM + bias + residual + LayerNorm, BM=32 -> 256 blocks (1/CU).
// ---------------------------------------------------------------------------
template<bool WRITE_BF>
__global__ __launch_bounds__(256)
void gemm_ln32(const short* __restrict__ A, const short* __restrict__ Bw,
               const float* __restrict__ biasv, const float* __restrict__ add,
               const float* __restrict__ gw, const float* __restrict__ be,
               float* __restrict__ outf, short* __restrict__ outb, int K)
{
    __shared__ short As[2][32 * 32];
    __shared__ short Bs[2][256 * 32];
    __shared__ float redS[2][16][2], redQ[2][16][2];

    const int t    = threadIdx.x;
    const int lane = t & 63;
    const int w    = t >> 6;
    const int quad = lane >> 4, l15 = lane & 15;
    const int wr   = w >> 1;          // row group: rows 16*wr .. 16*wr+15
    const int wg   = w & 1;           // column half: cols wg*128 .. +128
    const int m0   = blockIdx.x * 32;

    const int srow = lane >> 2;
    const int scol = (lane & 3) * 8;

    v4f acc[8];
    #pragma unroll
    for (int j = 0; j < 8; ++j) acc[j] = (v4f){0.f, 0.f, 0.f, 0.f};

    const int NK = K >> 5;

    auto stage = [&](int buf, int kt) {
        if (w < 2)   // A: 32 rows, waves 0,1
            async_copy16(A + (size_t)(m0 + 16 * w + srow) * K + kt + scol,
                         &As[buf][w * 512]);
        #pragma unroll
        for (int u = 0; u < 4; ++u) {   // B: 256 rows, 4 DMAs/thread
            const int e0 = (w * 4 + u) * 512;
            async_copy16(Bw + (size_t)((e0 >> 5) + srow) * K + kt + scol,
                         &Bs[buf][e0]);
        }
    };

    stage(0, 0);

    for (int it = 0; it < NK; ++it) {
        __syncthreads();
        if (it + 1 < NK) stage((it + 1) & 1, (it + 1) << 5);

        const int buf = it & 1;
        const v8s af = *(const v8s*)&As[buf][(16 * wr + l15) * 32 + quad * 8];
        #pragma unroll
        for (int j = 0; j < 8; ++j) {
            const v8s bfr = *(const v8s*)&Bs[buf][(wg * 128 + 16 * j + l15) * 32 + quad * 8];
            acc[j] = __builtin_amdgcn_mfma_f32_16x16x32_bf16(af, bfr, acc[j], 0, 0, 0);
        }
    }

    float v[4][8];
    #pragma unroll
    for (int rr = 0; rr < 4; ++rr) {
        const int row = m0 + 16 * wr + quad * 4 + rr;
        float s = 0.f, sq = 0.f;
        #pragma unroll
        for (int j = 0; j < 8; ++j) {
            const int n = wg * 128 + 16 * j + l15;
            const float x = acc[j][rr] + biasv[n] + add[(size_t)row * CD + n];
            v[rr][j] = x;
            s += x; sq += x * x;
        }
        #pragma unroll
        for (int off = 1; off < 16; off <<= 1) {
            s  += __shfl_xor(s, off);
            sq += __shfl_xor(sq, off);
        }
        if (l15 == 0) {
            redS[wr][quad * 4 + rr][wg] = s;
            redQ[wr][quad * 4 + rr][wg] = sq;
        }
    }
    __syncthreads();

    #pragma unroll
    for (int rr = 0; rr < 4; ++rr) {
        const int r16 = quad * 4 + rr;
        const int row = m0 + 16 * wr + r16;
        const float s  = redS[wr][r16][0] + redS[wr][r16][1];
        const float sq = redQ[wr][r16][0] + redQ[wr][r16][1];
        const float mean = s * (1.f / CD);
        const float var  = sq * (1.f / CD) - mean * mean;
        const float rstd = rsqrtf(var + CEPS);
        #pragma unroll
        for (int j = 0; j < 8; ++j) {
            const int n = wg * 128 + 16 * j + l15;
            const float y = (v[rr][j] - mean) * rstd * gw[n] + be[n];
            outf[(size_t)row * CD + n] = y;
            if (WRITE_BF) outb[(size_t)row * CD + n] = f2bf(y);
        }
    }
}

// ---------------------------------------------------------------------------
// Prep: src->bf16, weight transposes via 64x64 LDS tiles, biases packed.
// ---------------------------------------------------------------------------
__global__ __launch_bounds__(256)
void prep(const float* __restrict__ src,
          const float* __restrict__ Wq, const float* __restrict__ Wk,
          const float* __restrict__ Wv, const float* __restrict__ Wo,
          const float* __restrict__ W1, const float* __restrict__ W2,
          const float* __restrict__ bq, const float* __restrict__ bk,
          const float* __restrict__ bv, const float* __restrict__ bo,
          const float* __restrict__ b1, const float* __restrict__ b2,
          short* __restrict__ src_bf,
          short* __restrict__ wqkvT, short* __restrict__ woT,
          short* __restrict__ w1T, short* __restrict__ w2T,
          float* __restrict__ bpack)
{
    __shared__ float tile[64][65];
    const int bx = blockIdx.x, t = threadIdx.x;
    if (bx < 2048) {                                   // src cast: 512K float4
        const int i = bx * 256 + t;
        const float4 v = ((const float4*)src)[i];
        short4 o;
        o.x = f2bf(v.x); o.y = f2bf(v.y); o.z = f2bf(v.z); o.w = f2bf(v.w);
        ((short4*)src_bf)[i] = o;
    } else if (bx < 2288) {                            // weight transposes
        const int tt = bx - 2048;
        const float* S; short* D;
        int Sstride, Dstride, k0, srccol, dstrow;
        if (tt < 96) {                                 // wqkv: 24x4 tiles
            const int tk = tt & 3, tn = tt >> 2;
            const int ng = tn * 64;
            Sstride = 256; Dstride = 256; k0 = tk * 64;
            dstrow = tn * 64; D = wqkvT;
            if (ng < 256)      { S = Wq; srccol = ng; }
            else if (ng < 512) { S = Wk; srccol = ng - 256; }
            else { const int r = (ng - 512) >> 8;
                   S = Wv + (size_t)r * 65536; srccol = (ng - 512) & 255; }
        } else if (tt < 112) {                         // wo: 4x4
            const int u = tt - 96, tk = u & 3, tn = u >> 2;
            S = Wo; Sstride = 256; D = woT; Dstride = 256;
            k0 = tk * 64; srccol = tn * 64; dstrow = tn * 64;
        } else if (tt < 176) {                         // w1: 16x4
            const int u = tt - 112, tk = u & 3, tn = u >> 2;
            S = W1; Sstride = 1024; D = w1T; Dstride = 256;
            k0 = tk * 64; srccol = tn * 64; dstrow = tn * 64;
        } else {                                       // w2: 4x16
            const int u = tt - 176, tk = u & 15, tn = u >> 4;
            S = W2; Sstride = 256; D = w2T; Dstride = 1024;
            k0 = tk * 64; srccol = tn * 64; dstrow = tn * 64;
        }
        #pragma unroll
        for (int u2 = 0; u2 < 4; ++u2) {               // coalesced read
            const int kl = (t >> 4) + u2 * 16;
            const int nl = (t & 15) * 4;
            const float4 v = *(const float4*)&S[(size_t)(k0 + kl) * Sstride + srccol + nl];
            tile[kl][nl + 0] = v.x; tile[kl][nl + 1] = v.y;
            tile[kl][nl + 2] = v.z; tile[kl][nl + 3] = v.w;
        }
        __syncthreads();
        #pragma unroll
        for (int u2 = 0; u2 < 4; ++u2) {               // coalesced write
            const int nl = (t >> 4) + u2 * 16;
            const int kl = (t & 15) * 4;
            short4 o;
            o.x = f2bf(tile[kl + 0][nl]); o.y = f2bf(tile[kl + 1][nl]);
            o.z = f2bf(tile[kl + 2][nl]); o.w = f2bf(tile[kl + 3][nl]);
            *(short4*)&D[(size_t)(dstrow + nl) * Dstride + k0 + kl] = o;
        }
    } else {                                           // biases: 3072
        const int idx = (bx - 2288) * 256 + t;
        float bvv;
        if (idx < 256)       bvv = bq[idx];
        else if (idx < 512)  bvv = bk[idx - 256];
        else if (idx < 1536) bvv = bv[idx - 512];
        else if (idx < 1792) bvv = bo[idx - 1536];
        else if (idx < 2816) bvv = b1[idx - 1792];
        else                 bvv = b2[idx - 2816];
        bpack[idx] = bvv;
    }
}

// ---------------------------------------------------------------------------
// Fused relational attention with REGISTER-PREFETCH pipeline + 4-bit adj.
// Per tile: barrier A (prev compute done; prefetched loads long since landed)
// -> publish V/adj regs to LDS -> barrier B -> issue K-DMA (dbuf ks) + V/adj
// loads for NEXT tile -> compute.  Inter-barrier region = ds_writes only.
// ---------------------------------------------------------------------------
__global__ __launch_bounds__(256)
void attn_mfma(const short* __restrict__ qg, const short* __restrict__ kg,
               const short* __restrict__ vt, const unsigned char* __restrict__ adj4,
               short* __restrict__ outh)
{
    __shared__ __align__(16) short ks[2][64 * 32];      // K tiles (dbuf, DMA)
    __shared__ __align__(16) short vtile[4][32][72];    // V^T tiles [r][d][j]
    __shared__ __align__(16) short ps[64][68];          // P tile [i][j]
    __shared__ __align__(16) unsigned char adjs[64][40];// packed adj [i][j/2]
    __shared__ int lut[64][4];                          // (v0|v1<<3) -> selectors

    const int t    = threadIdx.x;
    const int lane = t & 63;
    const int w    = t >> 6;          // wave 0..3
    const int quad = lane >> 4;
    const int l15  = lane & 15;
    const int i0   = blockIdx.x * 64;
    const int h    = blockIdx.y;
    const int b    = blockIdx.z;
    const int bhh  = b * CH + h;
    const size_t bh = (size_t)bhh;

    if (t < 64) {
        const int b0 = t & 7, b1 = t >> 3;
        #pragma unroll
        for (int r = 0; r < 4; ++r) {
            const int lo = (b0 == r) ? 0x0100 : 0x0c0c;
            const int hi = (b1 == r) ? 0x0302 : 0x0c0c;
            lut[t][r] = lo | (hi << 16);
        }
    }

    const v8s qfrag = *(const v8s*)&qg[(bh * CN + i0 + 16 * w + l15) * CDH + quad * 8];

    v4f oacc[2];
    oacc[0] = (v4f){0.f, 0.f, 0.f, 0.f};
    oacc[1] = (v4f){0.f, 0.f, 0.f, 0.f};
    float plsum[4] = {0.f, 0.f, 0.f, 0.f};

    const float cs = 0.25503480f;     // (1/sqrt(32)) * log2(e)
    const int arow = 16 * w + l15;    // this lane's P/adj row (wave-private)

    const int srow = lane >> 2;            // K: row within wave-issue
    const int scol = (lane & 3) * 8;       // K: 8-elem chunk
    const int vd0  = lane >> 3;            // V: base d (0..7), +8*it
    const int vc   = (lane & 7) * 8;       // V: j chunk
    const short* vplane = vt + (((size_t)(w * 64 + bhh)) * CDH) * CN;  // wave w -> relation w
    // packed adj: row stride CN/2 = 512 B; this thread stages row t>>2, 8B chunk
    const unsigned char* adjg =
        adj4 + ((size_t)(b * CN) + i0 + (t >> 2)) * (CN / 2) + (t & 3) * 8;

    v8s vpre[4];
    int2 apre;

    // ---- prologue: prefetch tile 0 ----
    async_copy16(kg + (bh * CN + 16 * w + srow) * CDH + scol,
                 &ks[0][(16 * w + srow) * 32]);
    #pragma unroll
    for (int it = 0; it < 4; ++it)
        vpre[it] = *(const v8s*)&vplane[(size_t)(vd0 + 8 * it) * CN + vc];
    apre = *(const int2*)adjg;

    for (int jt = 0; jt < 16; ++jt) {
        __syncthreads();   // A: prev compute done; this tile's loads landed

        // publish V/adj for tile jt from registers (cheap: LDS writes only)
        #pragma unroll
        for (int it = 0; it < 4; ++it)
            *(v8s*)&vtile[w][vd0 + 8 * it][vc] = vpre[it];
        *(int2*)&adjs[t >> 2][(t & 3) * 8] = apre;
        __syncthreads();   // B: tile published

        // issue next tile's loads (fly during compute)
        if (jt + 1 < 16) {
            const int j1 = (jt + 1) * 64;
            async_copy16(kg + (bh * CN + j1 + 16 * w + srow) * CDH + scol,
                         &ks[(jt + 1) & 1][(16 * w + srow) * 32]);
            #pragma unroll
            for (int it = 0; it < 4; ++it)
                vpre[it] = *(const v8s*)&vplane[(size_t)(vd0 + 8 * it) * CN + j1 + vc];
            apre = *(const int2*)(adjg + (jt + 1) * 32);
        }

        // ---- scores: 4 MFMA per wave ----
        const short* ksb = ks[jt & 1];
        v4f sacc[4];
        #pragma unroll
        for (int jb = 0; jb < 4; ++jb) {
            const v8s kfrag = *(const v8s*)&ksb[(16 * jb + l15) * 32 + quad * 8];
            sacc[jb] = __builtin_amdgcn_mfma_f32_16x16x32_bf16(
                qfrag, kfrag, (v4f){0.f, 0.f, 0.f, 0.f}, 0, 0, 0);
        }

        // ---- fixed-max softmax ----
        #pragma unroll
        for (int rr = 0; rr < 4; ++rr) {
            const int prow = 16 * w + quad * 4 + rr;
            float p[4];
            #pragma unroll
            for (int jb = 0; jb < 4; ++jb) p[jb] = exp2f(cs * sacc[jb][rr]);
            plsum[rr] += (p[0] + p[1]) + (p[2] + p[3]);
            #pragma unroll
            for (int jb = 0; jb < 4; ++jb)
                ps[prow][16 * jb + l15] = f2bf(p[jb]);
        }

        // ---- PV: LUT+perm masked fragments (4-bit adj) ----
        #pragma unroll
        for (int kb = 0; kb < 2; ++kb) {
            const int4 praw = *(const int4*)&ps[arow][32 * kb + quad * 8];
            const int ab32 = *(const int*)&adjs[arow][16 * kb + quad * 4];
            const int P[4] = {praw.x, praw.y, praw.z, praw.w};
            int pf[4][4];
            #pragma unroll
            for (int u = 0; u < 4; ++u) {
                const int byte = (ab32 >> (8 * u)) & 0xff;
                const int idx = (byte & 7) | ((byte >> 1) & 0x38);
                const int4 sel = *(const int4*)&lut[idx][0];
                pf[0][u] = __builtin_amdgcn_perm(P[u], P[u], sel.x);
                pf[1][u] = __builtin_amdgcn_perm(P[u], P[u], sel.y);
                pf[2][u] = __builtin_amdgcn_perm(P[u], P[u], sel.z);
                pf[3][u] = __builtin_amdgcn_perm(P[u], P[u], sel.w);
            }
            #pragma unroll
            for (int r = 0; r < 4; ++r) {
                const v8s pfr = __builtin_bit_cast(v8s,
                    make_int4(pf[r][0], pf[r][1], pf[r][2], pf[r][3]));
                #pragma unroll
                for (int cb = 0; cb < 2; ++cb) {
                    const v8s vfrag = *(const v8s*)&vtile[r][16 * cb + l15][32 * kb + quad * 8];
                    oacc[cb] = __builtin_amdgcn_mfma_f32_16x16x32_bf16(
                        pfr, vfrag, oacc[cb], 0, 0, 0);
                }
            }
        }
    }

    // ---- epilogue ----
    #pragma unroll
    for (int rr = 0; rr < 4; ++rr) {
        float l = plsum[rr];
        #pragma unroll
        for (int off = 1; off < 16; off <<= 1) l += __shfl_xor(l, off);
        const float inv = 1.f / l;
        const int row = i0 + 16 * w + quad * 4 + rr;
        #pragma unroll
        for (int cb = 0; cb < 2; ++cb)
            outh[((size_t)b * CN + row) * CD + h * CDH + 16 * cb + l15] =
                f2bf(oacc[cb][rr] * inv);
    }
}

// ---------------------------------------------------------------------------
extern "C" void kernel_launch(void* const* d_in, const int* in_sizes, int n_in,
                              void* d_out, int out_size, void* d_ws, size_t ws_size,
                              hipStream_t stream)
{
    const float* src = (const float*)d_in[0];
    const int*   adj = (const int*)d_in[1];
    const float* Wq  = (const float*)d_in[2];
    const float* bq  = (const float*)d_in[3];
    const float* Wk  = (const float*)d_in[4];
    const float* bk  = (const float*)d_in[5];
    const float* Wv  = (const float*)d_in[6];
    const float* bv  = (const float*)d_in[7];
    const float* Wo  = (const float*)d_in[8];
    const float* bo  = (const float*)d_in[9];
    const float* W1  = (const float*)d_in[10];
    const float* b1  = (const float*)d_in[11];
    const float* W2  = (const float*)d_in[12];
    const float* b2  = (const float*)d_in[13];
    const float* g1  = (const float*)d_in[14];
    const float* be1 = (const float*)d_in[15];
    const float* g2  = (const float*)d_in[16];
    const float* be2 = (const float*)d_in[17];
    float* out = (float*)d_out;

    char* wsb = (char*)d_ws;
    const size_t MB = (size_t)1 << 20;

    // workspace layout (50 MB with aliasing)
    unsigned char* adj4 = (unsigned char*)(wsb);            // [0,4) MB packed adj
    short* qkv_bf = (short*)(wsb + 8 * MB);                 // [8,32): q,k planes + vT
    short* src_bf = (short*)(wsb + 32 * MB);                // [32,36)
    short* wqkvT  = (short*)(wsb + 36 * MB);                // 768 KB
    short* woT    = (short*)(wsb + 36 * MB + 768 * 1024);   // 128 KB
    short* w1T    = (short*)(wsb + 36 * MB + 896 * 1024);   // 512 KB
    short* w2T    = (short*)(wsb + 36 * MB + 1408 * 1024);  // 512 KB
    float* bpack  = (float*)(wsb + 36 * MB + 1920 * 1024);  // 12 KB
    short* heads_bf = (short*)(wsb + 38 * MB);              // [38,42)
    float* xres   = (float*)(wsb + 42 * MB);                // [42,50): LN1 fp32
    short* x_bf   = (short*)(wsb + 32 * MB);                // reuse src_bf
    short* h1_bf  = (short*)(wsb + 16 * MB);                // reuse vT (dead post-attn)

    const int M = CB * CN;        // 8192
    dim3 blk(256);

    // prep: src cast, coalesced weight transposes, biases (2300 blocks)
    prep<<<dim3(2300), blk, 0, stream>>>(src, Wq, Wk, Wv, Wo, W1, W2,
        bq, bk, bv, bo, b1, b2, src_bf, wqkvT, woT, w1T, w2T, bpack);

    // fused QK + V^T projection + 4-bit adj pack: 2048 blocks
    proj_kernel<<<dim3(2048), blk, 24576, stream>>>(
        src_bf, wqkvT, bpack, qkv_bf, adj, adj4);

    // fused relational MFMA attention (reg-prefetch pipeline) -> bf16 heads
    attn_mfma<<<dim3(CN / 64, CH, CB), blk, 0, stream>>>(
        qkv_bf, qkv_bf + SZH, qkv_bf + 2 * SZH, adj4, heads_bf);

    // O-projection + bias + residual(src) + LN1 -> xres fp32 + x_bf bf16
    gemm_ln32<true><<<dim3(M / 32), blk, 0, stream>>>(
        heads_bf, woT, bpack + 1536, src, g1, be1, xres, x_bf, CD);

    // FFN1: 1024 blocks
    gemm_mfma<64, 128, MODE_FFN1><<<dim3(M / 64, CFF / 128), blk, 24576, stream>>>(
        x_bf, w1T, bpack + 1792, h1_bf, M, CD, CFF);

    // FFN2 + bias + residual(xres) + LN2 -> out fp32
    gemm_ln32<false><<<dim3(M / 32), blk, 0, stream>>>(
        h1_bf, w2T, bpack + 2816, xres, g2, be2, out, nullptr, CFF);
}

// Round 12
// 235.871 us; speedup vs baseline: 1.0818x; 1.0096x over previous
//
#include <hip/hip_runtime.h>
#include <hip/hip_bf16.h>
#include <cmath>

// Problem constants (fixed by the reference)
constexpr int CB  = 8;     // batch
constexpr int CN  = 1024;  // sequence length
constexpr int CD  = 256;   // model dim
constexpr int CH  = 8;     // heads
constexpr int CDH = 32;    // head dim
constexpr int CR  = 4;     // relation types (adj value 4 = none)
constexpr int CFF = 1024;  // ffn dim
constexpr float CEPS = 1e-5f;
constexpr size_t SZH = (size_t)CB * CH * CN * CDH;  // 2M: one head-plane

#define MODE_QK    0   // scatter bf16 q/k head-major planes, +bias (cols 0..511)
#define MODE_FFN1  2   // +bias, tanh-gelu -> bf16
#define MODE_VT    4   // V^T gemm (A=weight rows, B=src rows): coalesced store

typedef float v4f __attribute__((ext_vector_type(4)));
typedef short v8s __attribute__((ext_vector_type(8)));

static __device__ __forceinline__ short f2bf(float f) {
    unsigned u = __builtin_bit_cast(unsigned, f);
    u += 0x7fff + ((u >> 16) & 1);          // round-to-nearest-even
    return (short)(u >> 16);
}
static __device__ __forceinline__ float bf2f(short s) {
    unsigned u = ((unsigned)(unsigned short)s) << 16;
    return __builtin_bit_cast(float, u);
}

static __device__ __forceinline__ void async_copy16(const void* g, void* l) {
    __builtin_amdgcn_global_load_lds(
        (const __attribute__((address_space(1))) void*)g,
        (__attribute__((address_space(3))) void*)l, 16, 0, 0);
}

// ---------------------------------------------------------------------------
// bf16 MFMA GEMM body (device fn, dynamic LDS): epilogue(A[M,K] @ Bw[N,K])
// BM x BN tile, 4 waves 2x2, BK=32 double-buffered 1-deep prefetch.
// ---------------------------------------------------------------------------
template<int BM, int BN, int MODE>
__device__ __forceinline__ void gemm_body(
    const short* __restrict__ A, const short* __restrict__ Bw,
    const float* __restrict__ biasv, void* __restrict__ dest,
    int M, int K, int Nw, int bx, int by, short* smem)
{
    constexpr int WTM = BM / 2, WTN = BN / 2;
    constexpr int TM = WTM / 16, TN = WTN / 16;
    short* As = smem;                    // [2][BM*32]
    short* Bs = smem + 2 * BM * 32;      // [2][BN*32]

    const int t    = threadIdx.x;
    const int lane = t & 63;
    const int w    = t >> 6;
    const int quad = lane >> 4, l15 = lane & 15;
    const int wm = w >> 1, wn = w & 1;
    const int m0 = bx * BM, n0 = by * BN;

    const int srow = lane >> 2;
    const int scol = (lane & 3) * 8;

    v4f acc[TM][TN];
    #pragma unroll
    for (int i = 0; i < TM; ++i)
        #pragma unroll
        for (int j = 0; j < TN; ++j) acc[i][j] = (v4f){0.f, 0.f, 0.f, 0.f};

    const int NK = K >> 5;

    auto stage = [&](int buf, int kt) {
        #pragma unroll
        for (int u = 0; u < BM / 64; ++u) {
            const int e0 = (w * (BM / 64) + u) * 512;
            const int row = (e0 >> 5) + srow;
            async_copy16(A + (size_t)(m0 + row) * K + kt + scol,
                         &As[buf * BM * 32 + e0]);
        }
        #pragma unroll
        for (int u = 0; u < BN / 64; ++u) {
            const int e0 = (w * (BN / 64) + u) * 512;
            const int row = (e0 >> 5) + srow;
            async_copy16(Bw + (size_t)(n0 + row) * K + kt + scol,
                         &Bs[buf * BN * 32 + e0]);
        }
    };

    stage(0, 0);

    for (int it = 0; it < NK; ++it) {
        __syncthreads();
        if (it + 1 < NK) stage((it + 1) & 1, (it + 1) << 5);

        const int buf = it & 1;
        v8s af[TM], bfr[TN];
        #pragma unroll
        for (int i = 0; i < TM; ++i)
            af[i] = *(const v8s*)&As[buf * BM * 32 +
                                     (wm * WTM + i * 16 + l15) * 32 + quad * 8];
        #pragma unroll
        for (int j = 0; j < TN; ++j)
            bfr[j] = *(const v8s*)&Bs[buf * BN * 32 +
                                      (wn * WTN + j * 16 + l15) * 32 + quad * 8];
        #pragma unroll
        for (int i = 0; i < TM; ++i)
            #pragma unroll
            for (int j = 0; j < TN; ++j)
                acc[i][j] = __builtin_amdgcn_mfma_f32_16x16x32_bf16(
                    af[i], bfr[j], acc[i][j], 0, 0, 0);
    }

    #pragma unroll
    for (int i = 0; i < TM; ++i) {
        #pragma unroll
        for (int j = 0; j < TN; ++j) {
            const int mb = m0 + wm * WTM + i * 16 + quad * 4;   // row of rr=0
            const int n  = n0 + wn * WTN + j * 16 + l15;
            float vals[4];
            if (MODE == MODE_VT) {
                #pragma unroll
                for (int rr = 0; rr < 4; ++rr) vals[rr] = acc[i][j][rr] + biasv[mb + rr];
            } else {
                #pragma unroll
                for (int rr = 0; rr < 4; ++rr) vals[rr] = acc[i][j][rr] + biasv[n];
            }

            if (MODE == MODE_QK) {
                const int b = mb >> 10, ii0 = mb & 1023;
                const int plane = n >> 8, nn = n & 255;
                const int h = nn >> 5, d = nn & 31;
                #pragma unroll
                for (int rr = 0; rr < 4; ++rr)
                    ((short*)dest)[(size_t)plane * SZH +
                        (((size_t)(b * CH + h)) * CN + ii0 + rr) * CDH + d] =
                        f2bf(vals[rr]);
            } else if (MODE == MODE_VT) {
                const int b = n >> 10, ii = n & 1023;
                #pragma unroll
                for (int rr = 0; rr < 4; ++rr) {
                    const int m = mb + rr;
                    const int r2 = m >> 8, hd = m & 255;
                    const int h = hd >> 5, d = hd & 31;
                    ((short*)dest)[2 * SZH +
                        (((size_t)(r2 * 64 + b * CH + h)) * CDH + d) * CN + ii] =
                        f2bf(vals[rr]);
                }
            } else { // MODE_FFN1: tanh-gelu -> bf16 (x*E/(E+1))
                #pragma unroll
                for (int rr = 0; rr < 4; ++rr) {
                    const size_t idx = (size_t)(mb + rr) * Nw + n;
                    const float xx = vals[rr];
                    const float E = exp2f(2.302217f * (xx + 0.044715f * xx * xx * xx));
                    ((short*)dest)[idx] = f2bf(xx * E / (E + 1.f));
                }
            }
        }
    }
}

template<int BM, int BN, int MODE>
__global__ __launch_bounds__(256)
void gemm_mfma(const short* __restrict__ A, const short* __restrict__ Bw,
               const float* __restrict__ biasv, void* __restrict__ dest,
               int M, int K, int Nw)
{
    extern __shared__ short smem[];
    gemm_body<BM, BN, MODE>(A, Bw, biasv, dest, M, K, Nw,
                            blockIdx.x, blockIdx.y, smem);
}

// ---------------------------------------------------------------------------
// Fused projection dispatch: blocks 0..511 = QK (8192x512), 512..1535 = V^T,
// 1536..2047 = adj int32 -> 4-BIT pack (2 values/byte).
// ---------------------------------------------------------------------------
__global__ __launch_bounds__(256)
void proj_kernel(const short* __restrict__ src_bf, const short* __restrict__ wqkvT,
                 const float* __restrict__ bpack, short* __restrict__ qkv,
                 const int* __restrict__ adj, unsigned char* __restrict__ adj4)
{
    extern __shared__ short smem[];
    const int g = blockIdx.x;
    if (g < 512) {
        gemm_body<64, 128, MODE_QK>(src_bf, wqkvT, bpack, qkv,
                                    8192, 256, 512, g >> 2, g & 3, smem);
    } else if (g < 1536) {
        const int h2 = g - 512;
        gemm_body<64, 128, MODE_VT>(wqkvT + 512 * 256, src_bf, bpack + 512,
                                    qkv, 1024, 256, 8192, h2 & 15, h2 >> 4, smem);
    } else {
        const int nout = CB * CN * CN / 8;           // 1M uints (8 values each)
        for (int i = (g - 1536) * 256 + threadIdx.x; i < nout; i += 512 * 256) {
            const int4 a0 = ((const int4*)adj)[2 * i];
            const int4 a1 = ((const int4*)adj)[2 * i + 1];
            const unsigned p =
                (unsigned)(a0.x & 0xf)        | ((unsigned)(a0.y & 0xf) << 4)  |
                ((unsigned)(a0.z & 0xf) << 8) | ((unsigned)(a0.w & 0xf) << 12) |
                ((unsigned)(a1.x & 0xf) << 16)| ((unsigned)(a1.y & 0xf) << 20) |
                ((unsigned)(a1.z & 0xf) << 24)| ((unsigned)(a1.w & 0xf) << 28);
            ((unsigned*)adj4)[i] = p;
        }
    }
}

// ---------------------------------------------------------------------------
// FUSED GEMM + bias + residual + LayerNorm, BM=32 -> 256 blocks (1/CU).
// OUTF: write fp32 result; OUTB: write bf16 result; ADDBF: residual is bf16.
// ---------------------------------------------------------------------------
template<bool OUTF, bool OUTB, bool ADDBF>
__global__ __launch_bounds__(256)
void gemm_ln32(const short* __restrict__ A, const short* __restrict__ Bw,
               const float* __restrict__ biasv, const void* __restrict__ addp,
               const float* __restrict__ gw, const float* __restrict__ be,
               float* __restrict__ outf, short* __restrict__ outb, int K)
{
    __shared__ short As[2][32 * 32];
    __shared__ short Bs[2][256 * 32];
    __shared__ float redS[2][16][2], redQ[2][16][2];

    const int t    = threadIdx.x;
    const int lane = t & 63;
    const int w    = t >> 6;
    const int quad = lane >> 4, l15 = lane & 15;
    const int wr   = w >> 1;          // row group: rows 16*wr .. 16*wr+15
    const int wg   = w & 1;           // column half: cols wg*128 .. +128
    const int m0   = blockIdx.x * 32;

    const int srow = lane >> 2;
    const int scol = (lane & 3) * 8;

    v4f acc[8];
    #pragma unroll
    for (int j = 0; j < 8; ++j) acc[j] = (v4f){0.f, 0.f, 0.f, 0.f};

    const int NK = K >> 5;

    auto stage = [&](int buf, int kt) {
        if (w < 2)   // A: 32 rows, waves 0,1
            async_copy16(A + (size_t)(m0 + 16 * w + srow) * K + kt + scol,
                         &As[buf][w * 512]);
        #pragma unroll
        for (int u = 0; u < 4; ++u) {   // B: 256 rows, 4 DMAs/thread
            const int e0 = (w * 4 + u) * 512;
            async_copy16(Bw + (size_t)((e0 >> 5) + srow) * K + kt + scol,
                         &Bs[buf][e0]);
        }
    };

    stage(0, 0);

    for (int it = 0; it < NK; ++it) {
        __syncthreads();
        if (it + 1 < NK) stage((it + 1) & 1, (it + 1) << 5);

        const int buf = it & 1;
        const v8s af = *(const v8s*)&As[buf][(16 * wr + l15) * 32 + quad * 8];
        #pragma unroll
        for (int j = 0; j < 8; ++j) {
            const v8s bfr = *(const v8s*)&Bs[buf][(wg * 128 + 16 * j + l15) * 32 + quad * 8];
            acc[j] = __builtin_amdgcn_mfma_f32_16x16x32_bf16(af, bfr, acc[j], 0, 0, 0);
        }
    }

    float v[4][8];
    #pragma unroll
    for (int rr = 0; rr < 4; ++rr) {
        const int row = m0 + 16 * wr + quad * 4 + rr;
        float s = 0.f, sq = 0.f;
        #pragma unroll
        for (int j = 0; j < 8; ++j) {
            const int n = wg * 128 + 16 * j + l15;
            const size_t idx = (size_t)row * CD + n;
            const float addv = ADDBF ? bf2f(((const short*)addp)[idx])
                                     : ((const float*)addp)[idx];
            const float x = acc[j][rr] + biasv[n] + addv;
            v[rr][j] = x;
            s += x; sq += x * x;
        }
        #pragma unroll
        for (int off = 1; off < 16; off <<= 1) {
            s  += __shfl_xor(s, off);
            sq += __shfl_xor(sq, off);
        }
        if (l15 == 0) {
            redS[wr][quad * 4 + rr][wg] = s;
            redQ[wr][quad * 4 + rr][wg] = sq;
        }
    }
    __syncthreads();

    #pragma unroll
    for (int rr = 0; rr < 4; ++rr) {
        const int r16 = quad * 4 + rr;
        const int row = m0 + 16 * wr + r16;
        const float s  = redS[wr][r16][0] + redS[wr][r16][1];
        const float sq = redQ[wr][r16][0] + redQ[wr][r16][1];
        const float mean = s * (1.f / CD);
        const float var  = sq * (1.f / CD) - mean * mean;
        const float rstd = rsqrtf(var + CEPS);
        #pragma unroll
        for (int j = 0; j < 8; ++j) {
            const int n = wg * 128 + 16 * j + l15;
            const float y = (v[rr][j] - mean) * rstd * gw[n] + be[n];
            if (OUTF) outf[(size_t)row * CD + n] = y;
            if (OUTB) outb[(size_t)row * CD + n] = f2bf(y);
        }
    }
}

// ---------------------------------------------------------------------------
// Prep: src->bf16, weight transposes via 64x64 LDS tiles, biases packed.
// ---------------------------------------------------------------------------
__global__ __launch_bounds__(256)
void prep(const float* __restrict__ src,
          const float* __restrict__ Wq, const float* __restrict__ Wk,
          const float* __restrict__ Wv, const float* __restrict__ Wo,
          const float* __restrict__ W1, const float* __restrict__ W2,
          const float* __restrict__ bq, const float* __restrict__ bk,
          const float* __restrict__ bv, const float* __restrict__ bo,
          const float* __restrict__ b1, const float* __restrict__ b2,
          short* __restrict__ src_bf,
          short* __restrict__ wqkvT, short* __restrict__ woT,
          short* __restrict__ w1T, short* __restrict__ w2T,
          float* __restrict__ bpack)
{
    __shared__ float tile[64][65];
    const int bx = blockIdx.x, t = threadIdx.x;
    if (bx < 2048) {                                   // src cast: 512K float4
        const int i = bx * 256 + t;
        const float4 v = ((const float4*)src)[i];
        short4 o;
        o.x = f2bf(v.x); o.y = f2bf(v.y); o.z = f2bf(v.z); o.w = f2bf(v.w);
        ((short4*)src_bf)[i] = o;
    } else if (bx < 2288) {                            // weight transposes
        const int tt = bx - 2048;
        const float* S; short* D;
        int Sstride, Dstride, k0, srccol, dstrow;
        if (tt < 96) {                                 // wqkv: 24x4 tiles
            const int tk = tt & 3, tn = tt >> 2;
            const int ng = tn * 64;
            Sstride = 256; Dstride = 256; k0 = tk * 64;
            dstrow = tn * 64; D = wqkvT;
            if (ng < 256)      { S = Wq; srccol = ng; }
            else if (ng < 512) { S = Wk; srccol = ng - 256; }
            else { const int r = (ng - 512) >> 8;
                   S = Wv + (size_t)r * 65536; srccol = (ng - 512) & 255; }
        } else if (tt < 112) {                         // wo: 4x4
            const int u = tt - 96, tk = u & 3, tn = u >> 2;
            S = Wo; Sstride = 256; D = woT; Dstride = 256;
            k0 = tk * 64; srccol = tn * 64; dstrow = tn * 64;
        } else if (tt < 176) {                         // w1: 16x4
            const int u = tt - 112, tk = u & 3, tn = u >> 2;
            S = W1; Sstride = 1024; D = w1T; Dstride = 256;
            k0 = tk * 64; srccol = tn * 64; dstrow = tn * 64;
        } else {                                       // w2: 4x16
            const int u = tt - 176, tk = u & 15, tn = u >> 4;
            S = W2; Sstride = 256; D = w2T; Dstride = 1024;
            k0 = tk * 64; srccol = tn * 64; dstrow = tn * 64;
        }
        #pragma unroll
        for (int u2 = 0; u2 < 4; ++u2) {               // coalesced read
            const int kl = (t >> 4) + u2 * 16;
            const int nl = (t & 15) * 4;
            const float4 v = *(const float4*)&S[(size_t)(k0 + kl) * Sstride + srccol + nl];
            tile[kl][nl + 0] = v.x; tile[kl][nl + 1] = v.y;
            tile[kl][nl + 2] = v.z; tile[kl][nl + 3] = v.w;
        }
        __syncthreads();
        #pragma unroll
        for (int u2 = 0; u2 < 4; ++u2) {               // coalesced write
            const int nl = (t >> 4) + u2 * 16;
            const int kl = (t & 15) * 4;
            short4 o;
            o.x = f2bf(tile[kl + 0][nl]); o.y = f2bf(tile[kl + 1][nl]);
            o.z = f2bf(tile[kl + 2][nl]); o.w = f2bf(tile[kl + 3][nl]);
            *(short4*)&D[(size_t)(dstrow + nl) * Dstride + k0 + kl] = o;
        }
    } else {                                           // biases: 3072
        const int idx = (bx - 2288) * 256 + t;
        float bvv;
        if (idx < 256)       bvv = bq[idx];
        else if (idx < 512)  bvv = bk[idx - 256];
        else if (idx < 1536) bvv = bv[idx - 512];
        else if (idx < 1792) bvv = bo[idx - 1536];
        else if (idx < 2816) bvv = b1[idx - 1792];
        else                 bvv = b2[idx - 2816];
        bpack[idx] = bvv;
    }
}

// ---------------------------------------------------------------------------
// Fused relational attention: reg-prefetch pipeline + 4-bit adj + XCD-AWARE
// 1D grid.  b = g & 7 so all 128 blocks of one batch land on the same XCD
// (round-robin dispatch): per-XCD working set = 8 heads' K/V (2.6 MB) +
// adj (0.5 MB) < 4 MB L2 -> K/V/adj become L2 hits after first touch.
// ---------------------------------------------------------------------------
__global__ __launch_bounds__(256)
void attn_mfma(const short* __restrict__ qg, const short* __restrict__ kg,
               const short* __restrict__ vt, const unsigned char* __restrict__ adj4,
               short* __restrict__ outh)
{
    __shared__ __align__(16) short ks[2][64 * 32];      // K tiles (dbuf, DMA)
    __shared__ __align__(16) short vtile[4][32][72];    // V^T tiles [r][d][j]
    __shared__ __align__(16) short ps[64][68];          // P tile [i][j]
    __shared__ __align__(16) unsigned char adjs[64][40];// packed adj [i][j/2]
    __shared__ int lut[64][4];                          // (v0|v1<<3) -> selectors

    const int t    = threadIdx.x;
    const int lane = t & 63;
    const int w    = t >> 6;          // wave 0..3
    const int quad = lane >> 4;
    const int l15  = lane & 15;
    const int g    = blockIdx.x;      // 1D grid, XCD-aware decode
    const int b    = g & 7;           // same XCD for whole batch
    const int h    = (g >> 3) & 7;
    const int i0   = (g >> 6) * 64;
    const int bhh  = b * CH + h;
    const size_t bh = (size_t)bhh;

    if (t < 64) {
        const int b0 = t & 7, b1 = t >> 3;
        #pragma unroll
        for (int r = 0; r < 4; ++r) {
            const int lo = (b0 == r) ? 0x0100 : 0x0c0c;
            const int hi = (b1 == r) ? 0x0302 : 0x0c0c;
            lut[t][r] = lo | (hi << 16);
        }
    }

    const v8s qfrag = *(const v8s*)&qg[(bh * CN + i0 + 16 * w + l15) * CDH + quad * 8];

    v4f oacc[2];
    oacc[0] = (v4f){0.f, 0.f, 0.f, 0.f};
    oacc[1] = (v4f){0.f, 0.f, 0.f, 0.f};
    float plsum[4] = {0.f, 0.f, 0.f, 0.f};

    const float cs = 0.25503480f;     // (1/sqrt(32)) * log2(e)
    const int arow = 16 * w + l15;    // this lane's P/adj row (wave-private)

    const int srow = lane >> 2;            // K: row within wave-issue
    const int scol = (lane & 3) * 8;       // K: 8-elem chunk
    const int vd0  = lane >> 3;            // V: base d (0..7), +8*it
    const int vc   = (lane & 7) * 8;       // V: j chunk
    const short* vplane = vt + (((size_t)(w * 64 + bhh)) * CDH) * CN;  // wave w -> relation w
    const unsigned char* adjg =
        adj4 + ((size_t)(b * CN) + i0 + (t >> 2)) * (CN / 2) + (t & 3) * 8;

    v8s vpre[4];
    int2 apre;

    // ---- prologue: prefetch tile 0 ----
    async_copy16(kg + (bh * CN + 16 * w + srow) * CDH + scol,
                 &ks[0][(16 * w + srow) * 32]);
    #pragma unroll
    for (int it = 0; it < 4; ++it)
        vpre[it] = *(const v8s*)&vplane[(size_t)(vd0 + 8 * it) * CN + vc];
    apre = *(const int2*)adjg;

    for (int jt = 0; jt < 16; ++jt) {
        __syncthreads();   // A: prev compute done; this tile's loads landed

        #pragma unroll
        for (int it = 0; it < 4; ++it)
            *(v8s*)&vtile[w][vd0 + 8 * it][vc] = vpre[it];
        *(int2*)&adjs[t >> 2][(t & 3) * 8] = apre;
        __syncthreads();   // B: tile published

        if (jt + 1 < 16) {
            const int j1 = (jt + 1) * 64;
            async_copy16(kg + (bh * CN + j1 + 16 * w + srow) * CDH + scol,
                         &ks[(jt + 1) & 1][(16 * w + srow) * 32]);
            #pragma unroll
            for (int it = 0; it < 4; ++it)
                vpre[it] = *(const v8s*)&vplane[(size_t)(vd0 + 8 * it) * CN + j1 + vc];
            apre = *(const int2*)(adjg + (jt + 1) * 32);
        }

        // ---- scores: 4 MFMA per wave ----
        const short* ksb = ks[jt & 1];
        v4f sacc[4];
        #pragma unroll
        for (int jb = 0; jb < 4; ++jb) {
            const v8s kfrag = *(const v8s*)&ksb[(16 * jb + l15) * 32 + quad * 8];
            sacc[jb] = __builtin_amdgcn_mfma_f32_16x16x32_bf16(
                qfrag, kfrag, (v4f){0.f, 0.f, 0.f, 0.f}, 0, 0, 0);
        }

        // ---- fixed-max softmax ----
        #pragma unroll
        for (int rr = 0; rr < 4; ++rr) {
            const int prow = 16 * w + quad * 4 + rr;
            float p[4];
            #pragma unroll
            for (int jb = 0; jb < 4; ++jb) p[jb] = exp2f(cs * sacc[jb][rr]);
            plsum[rr] += (p[0] + p[1]) + (p[2] + p[3]);
            #pragma unroll
            for (int jb = 0; jb < 4; ++jb)
                ps[prow][16 * jb + l15] = f2bf(p[jb]);
        }

        // ---- PV: LUT+perm masked fragments (4-bit adj) ----
        #pragma unroll
        for (int kb = 0; kb < 2; ++kb) {
            const int4 praw = *(const int4*)&ps[arow][32 * kb + quad * 8];
            const int ab32 = *(const int*)&adjs[arow][16 * kb + quad * 4];
            const int P[4] = {praw.x, praw.y, praw.z, praw.w};
            int pf[4][4];
            #pragma unroll
            for (int u = 0; u < 4; ++u) {
                const int byte = (ab32 >> (8 * u)) & 0xff;
                const int idx = (byte & 7) | ((byte >> 1) & 0x38);
                const int4 sel = *(const int4*)&lut[idx][0];
                pf[0][u] = __builtin_amdgcn_perm(P[u], P[u], sel.x);
                pf[1][u] = __builtin_amdgcn_perm(P[u], P[u], sel.y);
                pf[2][u] = __builtin_amdgcn_perm(P[u], P[u], sel.z);
                pf[3][u] = __builtin_amdgcn_perm(P[u], P[u], sel.w);
            }
            #pragma unroll
            for (int r = 0; r < 4; ++r) {
                const v8s pfr = __builtin_bit_cast(v8s,
                    make_int4(pf[r][0], pf[r][1], pf[r][2], pf[r][3]));
                #pragma unroll
                for (int cb = 0; cb < 2; ++cb) {
                    const v8s vfrag = *(const v8s*)&vtile[r][16 * cb + l15][32 * kb + quad * 8];
                    oacc[cb] = __builtin_amdgcn_mfma_f32_16x16x32_bf16(
                        pfr, vfrag, oacc[cb], 0, 0, 0);
                }
            }
        }
    }

    // ---- epilogue ----
    #pragma unroll
    for (int rr = 0; rr < 4; ++rr) {
        float l = plsum[rr];
        #pragma unroll
        for (int off = 1; off < 16; off <<= 1) l += __shfl_xor(l, off);
        const float inv = 1.f / l;
        const int row = i0 + 16 * w + quad * 4 + rr;
        #pragma unroll
        for (int cb = 0; cb < 2; ++cb)
            outh[((size_t)b * CN + row) * CD + h * CDH + 16 * cb + l15] =
                f2bf(oacc[cb][rr] * inv);
    }
}

// ---------------------------------------------------------------------------
extern "C" void kernel_launch(void* const* d_in, const int* in_sizes, int n_in,
                              void* d_out, int out_size, void* d_ws, size_t ws_size,
                              hipStream_t stream)
{
    const float* src = (const float*)d_in[0];
    const int*   adj = (const int*)d_in[1];
    const float* Wq  = (const float*)d_in[2];
    const float* bq  = (const float*)d_in[3];
    const float* Wk  = (const float*)d_in[4];
    const float* bk  = (const float*)d_in[5];
    const float* Wv  = (const float*)d_in[6];
    const float* bv  = (const float*)d_in[7];
    const float* Wo  = (const float*)d_in[8];
    const float* bo  = (const float*)d_in[9];
    const float* W1  = (const float*)d_in[10];
    const float* b1  = (const float*)d_in[11];
    const float* W2  = (const float*)d_in[12];
    const float* b2  = (const float*)d_in[13];
    const float* g1  = (const float*)d_in[14];
    const float* be1 = (const float*)d_in[15];
    const float* g2  = (const float*)d_in[16];
    const float* be2 = (const float*)d_in[17];
    float* out = (float*)d_out;

    char* wsb = (char*)d_ws;
    const size_t MB = (size_t)1 << 20;

    // workspace layout (42 MB with aliasing)
    unsigned char* adj4 = (unsigned char*)(wsb);            // [0,4) MB packed adj
    short* qkv_bf = (short*)(wsb + 8 * MB);                 // [8,32): q,k planes + vT
    short* src_bf = (short*)(wsb + 32 * MB);                // [32,36)
    short* wqkvT  = (short*)(wsb + 36 * MB);                // 768 KB
    short* woT    = (short*)(wsb + 36 * MB + 768 * 1024);   // 128 KB
    short* w1T    = (short*)(wsb + 36 * MB + 896 * 1024);   // 512 KB
    short* w2T    = (short*)(wsb + 36 * MB + 1408 * 1024);  // 512 KB
    float* bpack  = (float*)(wsb + 36 * MB + 1920 * 1024);  // 12 KB
    short* heads_bf = (short*)(wsb + 38 * MB);              // [38,42)
    short* x_bf   = (short*)(wsb + 32 * MB);                // reuse src_bf (LN1 out)
    short* h1_bf  = (short*)(wsb + 16 * MB);                // reuse vT (dead post-attn)

    const int M = CB * CN;        // 8192
    dim3 blk(256);

    // prep: src cast, coalesced weight transposes, biases (2300 blocks)
    prep<<<dim3(2300), blk, 0, stream>>>(src, Wq, Wk, Wv, Wo, W1, W2,
        bq, bk, bv, bo, b1, b2, src_bf, wqkvT, woT, w1T, w2T, bpack);

    // fused QK + V^T projection + 4-bit adj pack: 2048 blocks
    proj_kernel<<<dim3(2048), blk, 24576, stream>>>(
        src_bf, wqkvT, bpack, qkv_bf, adj, adj4);

    // fused relational MFMA attention (XCD-aware 1D grid) -> bf16 heads
    attn_mfma<<<dim3(1024), blk, 0, stream>>>(
        qkv_bf, qkv_bf + SZH, qkv_bf + 2 * SZH, adj4, heads_bf);

    // O-projection + bias + residual(src fp32) + LN1 -> x_bf bf16 only
    gemm_ln32<false, true, false><<<dim3(M / 32), blk, 0, stream>>>(
        heads_bf, woT, bpack + 1536, src, g1, be1, nullptr, x_bf, CD);

    // FFN1: 1024 blocks
    gemm_mfma<64, 128, MODE_FFN1><<<dim3(M / 64, CFF / 128), blk, 24576, stream>>>(
        x_bf, w1T, bpack + 1792, h1_bf, M, CD, CFF);

    // FFN2 + bias + residual(x_bf bf16) + LN2 -> out fp32
    gemm_ln32<true, false, true><<<dim3(M / 32), blk, 0, stream>>>(
        h1_bf, w2T, bpack + 2816, x_bf, g2, be2, out, nullptr, CFF);
}